// Round 3
// baseline (173.626 us; speedup 1.0000x reference)
//
#include <hip/hip_runtime.h>
#include <stdint.h>

typedef unsigned short u16;
typedef __attribute__((ext_vector_type(8))) short short8;
typedef __attribute__((ext_vector_type(4))) float f32x4;
typedef __attribute__((ext_vector_type(4))) unsigned short u16x4;

#define DEVI __device__ __forceinline__

DEVI u16 f2bf(float f) {
  uint32_t u = __builtin_bit_cast(uint32_t, f);
  u += 0x7fffu + ((u >> 16) & 1u);
  return (u16)(u >> 16);
}

DEVI void gload_lds16(const void* g, void* l) {
  __builtin_amdgcn_global_load_lds(
      (const __attribute__((address_space(1))) void*)g,
      (__attribute__((address_space(3))) void*)(uint32_t)(uintptr_t)l,
      16, 0, 0);
}

// ---------------- convert / concat fp32 -> bf16 ----------------
__global__ void cvt_cat_bf16(const float* __restrict__ a, const float* __restrict__ b,
                             u16* __restrict__ dst, long total) {
  for (long i = ((long)blockIdx.x * 256 + threadIdx.x) * 4; i < total;
       i += (long)gridDim.x * 1024) {
    const long row = i >> 11;
    const long c = i & 2047;
    const float* src = (c < 1024) ? (a + row * 1024 + c) : (b + row * 1024 + (c - 1024));
    const float4 v = *(const float4*)src;
    u16x4 o = {f2bf(v.x), f2bf(v.y), f2bf(v.z), f2bf(v.w)};
    *(u16x4*)(dst + i) = o;
  }
}

__global__ void cvt_bf16(const float* __restrict__ a, u16* __restrict__ dst, long total) {
  for (long i = ((long)blockIdx.x * 256 + threadIdx.x) * 4; i < total;
       i += (long)gridDim.x * 1024) {
    const float4 v = *(const float4*)(a + i);
    u16x4 o = {f2bf(v.x), f2bf(v.y), f2bf(v.z), f2bf(v.w)};
    *(u16x4*)(dst + i) = o;
  }
}

// ---------------- bf16 GEMM 128^2 (m97 structure) — used for proj ----------------
__global__ __launch_bounds__(256, 2)
void gemm_bt(const u16* __restrict__ A, const u16* __restrict__ B,
             float* __restrict__ C, const float* __restrict__ bias1,
             const float* __restrict__ bias2, int M, int N, int K) {
  __shared__ u16 As[128 * 32];
  __shared__ u16 Bs[128 * 32];
  const int t = threadIdx.x;
  const int w = t >> 6, l = t & 63;
  const int l15 = l & 15, lg = l >> 4;
  const int bm = blockIdx.x, bn = blockIdx.y;
  const int wr = (w >> 1) * 64, wc = (w & 1) * 64;
  f32x4 acc[4][4] = {};
  const int c0 = w * 64 + l;

  for (int kt = 0; kt < (K >> 5); ++kt) {
#pragma unroll
    for (int i = 0; i < 2; ++i) {
      const int c = i * 256 + c0;
      const int row = c >> 2, seg = c & 3;
      gload_lds16(A + (long)(bm * 128 + row) * K + kt * 32 + seg * 8,
                  (char*)As + w * 1024 + i * 4096);
      gload_lds16(B + (long)(bn * 128 + row) * K + kt * 32 + seg * 8,
                  (char*)Bs + w * 1024 + i * 4096);
    }
    __syncthreads();
    short8 af[4], bfr[4];
#pragma unroll
    for (int m = 0; m < 4; ++m)
      af[m] = *(const short8*)&As[(wr + m * 16 + l15) * 32 + lg * 8];
#pragma unroll
    for (int n = 0; n < 4; ++n)
      bfr[n] = *(const short8*)&Bs[(wc + n * 16 + l15) * 32 + lg * 8];
#pragma unroll
    for (int m = 0; m < 4; ++m)
#pragma unroll
      for (int n = 0; n < 4; ++n)
        acc[m][n] = __builtin_amdgcn_mfma_f32_16x16x32_bf16(af[m], bfr[n], acc[m][n], 0, 0, 0);
    __syncthreads();
  }
#pragma unroll
  for (int m = 0; m < 4; ++m) {
    const int row0 = bm * 128 + wr + m * 16 + lg * 4;
#pragma unroll
    for (int n = 0; n < 4; ++n) {
      const int col = bn * 128 + wc + n * 16 + l15;
      float bia = 0.f;
      if (bias1) bia += bias1[col];
      if (bias2) bia += bias2[col];
#pragma unroll
      for (int r = 0; r < 4; ++r)
        C[(long)(row0 + r) * N + col] = acc[m][n][r] + bia;
    }
  }
}

// ---------------- bf16 GEMM 256^2, 8 waves, 4-deep pipelined LDS, BK=32 ----------
// A [M,K], B [N,K] bf16 row-major; C [M,N] fp32 + bias. M%256==0, N%256==0, K%32==0,
// K/32 >= 4. LDS layout per tile buffer: pair-row swizzled —
// logical (row r, 16B-granule g) at physical row p=r>>1, slot s=(g+4*(r&1))^(p&7).
// ds_read_b128 fragments then hit each bank exactly twice per 16 lanes (2-way = free).
__global__ __launch_bounds__(512, 2)
void gemm256(const u16* __restrict__ A, const u16* __restrict__ B,
             float* __restrict__ C, const float* __restrict__ bias1,
             const float* __restrict__ bias2, int M, int N, int K) {
  __shared__ u16 lds[4][16384];  // 4 bufs x (A 256x32 | B 256x32) = 128 KiB
  const int t = threadIdx.x;
  const int w = t >> 6, l = t & 63;
  const int l15 = l & 15, lg = l >> 4;
  const int wr = w >> 2, wc = w & 3;  // 2 x 4 wave grid -> 128 x 64 per wave
  const int nbn = N >> 8;
  const int nb = gridDim.x;
  const int bid = blockIdx.x;
  // XCD-contiguous swizzle (bijective when nb % 8 == 0)
  const int lid = ((nb & 7) == 0) ? ((bid & 7) * (nb >> 3) + (bid >> 3)) : bid;
  const int bm = lid / nbn, bn = lid % nbn;
  const long rowA0 = (long)bm * 256;
  const long rowB0 = (long)bn * 256;
  const int nkt = K >> 5;

  // staging geometry (fixed per thread): lane l, issue i writes physical
  // p = i*64 + w*8 + (l>>3), slot = l&7  ->  logical r = i*128+w*16+rsub, g = sg
  const int su = (l & 7) ^ (l >> 3);
  const int rsub = 2 * (l >> 3) + (su >> 2);
  const int sg = su & 3;
  // fragment-read slot (same for A and B): row = rbase + l15, granule = lg
  const int sfr = (lg + 4 * (l15 & 1)) ^ (l15 >> 1);

  f32x4 acc[8][4] = {};

#define STAGE(KT)                                                              \
  {                                                                            \
    const int _b = (KT) & 3;                                                   \
    _Pragma("unroll") for (int i = 0; i < 2; ++i) {                            \
      const int r = i * 128 + w * 16 + rsub;                                   \
      gload_lds16(A + (rowA0 + r) * K + (KT) * 32 + sg * 8,                    \
                  (char*)&lds[_b][(i * 64 + w * 8) * 64]);                     \
      gload_lds16(B + (rowB0 + r) * K + (KT) * 32 + sg * 8,                    \
                  (char*)&lds[_b][8192 + (i * 64 + w * 8) * 64]);              \
    }                                                                          \
  }

#define TILE(KT, VMSTR, DO_STAGE)                                              \
  {                                                                            \
    asm volatile("s_waitcnt vmcnt(" VMSTR ")" ::: "memory");                   \
    __builtin_amdgcn_s_barrier();                                              \
    asm volatile("" ::: "memory");                                             \
    __builtin_amdgcn_sched_barrier(0);                                         \
    if (DO_STAGE) STAGE((KT) + 3);                                             \
    const u16* bufp = lds[(KT) & 3];                                           \
    short8 bfr[4];                                                             \
    _Pragma("unroll") for (int n = 0; n < 4; ++n) {                            \
      const int p = wc * 32 + n * 8 + (l15 >> 1);                              \
      bfr[n] = *(const short8*)&bufp[8192 + p * 64 + sfr * 8];                 \
    }                                                                          \
    __builtin_amdgcn_s_setprio(1);                                             \
    _Pragma("unroll") for (int m = 0; m < 8; ++m) {                            \
      const int p = wr * 64 + m * 8 + (l15 >> 1);                              \
      const short8 af = *(const short8*)&bufp[p * 64 + sfr * 8];               \
      _Pragma("unroll") for (int n = 0; n < 4; ++n)                            \
        acc[m][n] = __builtin_amdgcn_mfma_f32_16x16x32_bf16(af, bfr[n],        \
                                                            acc[m][n], 0, 0, 0); \
    }                                                                          \
    __builtin_amdgcn_s_setprio(0);                                             \
  }

  // prologue: stage tiles 0,1,2 (12 loads/thread in flight max)
  STAGE(0)
  STAGE(1)
  STAGE(2)
  // main loop: counted vmcnt(8) = tiles t+1,t+2 in flight; never drains
  for (int kt = 0; kt < nkt - 2; ++kt) TILE(kt, "8", (kt + 3 < nkt))
  // epilogue: drain 4 -> 0
  TILE(nkt - 2, "4", false)
  TILE(nkt - 1, "0", false)
#undef TILE
#undef STAGE

  // C write + bias
#pragma unroll
  for (int m = 0; m < 8; ++m) {
    const int row0 = bm * 256 + wr * 128 + m * 16 + lg * 4;
#pragma unroll
    for (int n = 0; n < 4; ++n) {
      const int col = bn * 256 + wc * 64 + n * 16 + l15;
      float bia = 0.f;
      if (bias1) bia += bias1[col];
      if (bias2) bia += bias2[col];
#pragma unroll
      for (int r = 0; r < 4; ++r)
        C[(long)(row0 + r) * N + col] = acc[m][n][r] + bia;
    }
  }
}

// ---------------- fuse: split qkv, vres mix, LN(q,k), RoPE ----------------
__global__ __launch_bounds__(256)
void fuse_qkv2(const float* __restrict__ qkv, const float* __restrict__ vres,
               const float* __restrict__ rope,
               const float* __restrict__ qg, const float* __restrict__ qb,
               const float* __restrict__ kg, const float* __restrict__ kb,
               const float* __restrict__ pl1, const float* __restrict__ pl2,
               u16* __restrict__ Q, u16* __restrict__ Ksw, u16* __restrict__ VTsw) {
  __shared__ u16 Vl[64][72];
  const int t = threadIdx.x, w = t >> 6, d = t & 63;
  const int bh = blockIdx.x, ntile = blockIdx.y;
  const int b = bh >> 4, h = bh & 15, n0 = ntile * 64;
  const float l1 = pl1[0], l2 = pl2[0];
  const float gq = qg[d], bq = qb[d];
  const float gk = kg[d], bk = kb[d];
  const float sgn = (d < 32) ? -1.f : 1.f;
  const int c = d >> 3, d7 = d & 7;

  for (int i = 0; i < 16; ++i) {
    const int nl = w * 16 + i;
    const int n = n0 + nl;
    const long base = ((long)(b * 1024 + n)) * 3072 + h * 64 + d;
    float q = qkv[base];
    float k = qkv[base + 1024];
    float v = qkv[base + 2048];
    v = l1 * v + l2 * vres[((long)(bh * 1024 + n)) * 64 + d];
    const float sinv = rope[n * 128 + d];
    const float cosv = rope[n * 128 + 64 + d];
    float s = q;
#pragma unroll
    for (int off = 1; off < 64; off <<= 1) s += __shfl_xor(s, off);
    const float qc = q - s * (1.f / 64.f);
    float vs = qc * qc;
#pragma unroll
    for (int off = 1; off < 64; off <<= 1) vs += __shfl_xor(vs, off);
    const float qn = qc * (1.f / sqrtf(vs * (1.f / 64.f) + 1e-5f)) * gq + bq;
    float s2 = k;
#pragma unroll
    for (int off = 1; off < 64; off <<= 1) s2 += __shfl_xor(s2, off);
    const float kc = k - s2 * (1.f / 64.f);
    float vs2 = kc * kc;
#pragma unroll
    for (int off = 1; off < 64; off <<= 1) vs2 += __shfl_xor(vs2, off);
    const float kn = kc * (1.f / sqrtf(vs2 * (1.f / 64.f) + 1e-5f)) * gk + bk;
    const float qo = __shfl_xor(qn, 32);
    const float ko = __shfl_xor(kn, 32);
    const float qr = qn * cosv + sgn * qo * sinv;
    const float kr = kn * cosv + sgn * ko * sinv;
    Q[(long)bh * 65536 + (long)n * 64 + d] = f2bf(qr);
    Ksw[(long)bh * 65536 + (long)n * 64 + ((c ^ (n & 7)) * 8 + d7)] = f2bf(kr);
    Vl[nl][d] = f2bf(v);
  }
  __syncthreads();
#pragma unroll
  for (int i = 0; i < 2; ++i) {
    const int task = i * 256 + t;
    const int dd = task >> 3, cc = task & 7;
    short8 o;
#pragma unroll
    for (int u = 0; u < 8; ++u) o[u] = (short)Vl[cc * 8 + u][dd];
    *(short8*)&VTsw[((long)(bh * 64 + dd)) * 1024 + n0 + ((cc ^ (dd & 7)) * 8)] = o;
  }
}

// ---------------- flash attention fwd: swapped QK^T and PV ----------------
__global__ __launch_bounds__(256, 4)
void attn_fwd2(const u16* __restrict__ Q, const u16* __restrict__ Ksw,
               const u16* __restrict__ VTsw, u16* __restrict__ Out) {
  __shared__ u16 Kl[64 * 64];
  __shared__ u16 Vl[64 * 64];
  __shared__ u16 Pl[4][16 * 64];
  const int t = threadIdx.x, w = t >> 6, l = t & 63;
  const int l15 = l & 15, lg = l >> 4;
  const int x7 = l15 & 7;
  const int bh = blockIdx.x, q0 = blockIdx.y * 64;
  const long bo = (long)bh * 65536;
  u16* Plw = &Pl[w][0];

  const int qrow = q0 + w * 16 + l15;
  short8 qf[2];
#pragma unroll
  for (int ks = 0; ks < 2; ++ks)
    qf[ks] = *(const short8*)&Q[bo + (long)qrow * 64 + ks * 32 + lg * 8];

  f32x4 acc[4] = {};
  float m_run = -1e30f, l_run = 0.f;

  for (int kv = 0; kv < 16; ++kv) {
    const int kvb = kv * 64;
#pragma unroll
    for (int i = 0; i < 2; ++i) {
      const int idx = i * 256 + t;
      const int row = idx >> 3, seg = idx & 7;
      gload_lds16(Ksw + bo + (long)(kvb + row) * 64 + seg * 8, (char*)Kl + idx * 16);
      gload_lds16(VTsw + bo + (long)row * 1024 + kvb + seg * 8, (char*)Vl + idx * 16);
    }
    __syncthreads();
    f32x4 p[4];
#pragma unroll
    for (int mt = 0; mt < 4; ++mt) {
      f32x4 ps = {};
#pragma unroll
      for (int ks = 0; ks < 2; ++ks) {
        const short8 kf =
            *(const short8*)&Kl[(mt * 16 + l15) * 64 + (((ks * 4 + lg) ^ x7) * 8)];
        ps = __builtin_amdgcn_mfma_f32_16x16x32_bf16(kf, qf[ks], ps, 0, 0, 0);
      }
      p[mt] = ps;
    }
    float mx = p[0][0];
#pragma unroll
    for (int mt = 0; mt < 4; ++mt)
#pragma unroll
      for (int r = 0; r < 4; ++r) mx = fmaxf(mx, p[mt][r]);
    mx = fmaxf(mx, __shfl_xor(mx, 16));
    mx = fmaxf(mx, __shfl_xor(mx, 32));
    const float mnew = fmaxf(m_run, mx * 0.125f);
    const float alpha = __expf(m_run - mnew);
    m_run = mnew;
    float sum = 0.f;
#pragma unroll
    for (int mt = 0; mt < 4; ++mt)
#pragma unroll
      for (int r = 0; r < 4; ++r) {
        const float e = __expf(p[mt][r] * 0.125f - mnew);
        p[mt][r] = e;
        sum += e;
      }
    sum += __shfl_xor(sum, 16);
    sum += __shfl_xor(sum, 32);
    l_run = l_run * alpha + sum;
#pragma unroll
    for (int mt = 0; mt < 4; ++mt) {
      const int c = mt * 2 + (lg >> 1);
      char* bp = (char*)Plw + l15 * 128 + ((c ^ x7) * 16) + (lg & 1) * 8;
      *(uint32_t*)bp = (uint32_t)f2bf(p[mt][0]) | ((uint32_t)f2bf(p[mt][1]) << 16);
      *(uint32_t*)(bp + 4) = (uint32_t)f2bf(p[mt][2]) | ((uint32_t)f2bf(p[mt][3]) << 16);
    }
#pragma unroll
    for (int mt = 0; mt < 4; ++mt)
#pragma unroll
      for (int r = 0; r < 4; ++r) acc[mt][r] *= alpha;
#pragma unroll
    for (int ks = 0; ks < 2; ++ks) {
      const short8 pf =
          *(const short8*)((char*)Plw + l15 * 128 + (((ks * 4 + lg) ^ x7) * 16));
#pragma unroll
      for (int mt = 0; mt < 4; ++mt) {
        const short8 vf =
            *(const short8*)&Vl[(mt * 16 + l15) * 64 + (((ks * 4 + lg) ^ x7) * 8)];
        acc[mt] = __builtin_amdgcn_mfma_f32_16x16x32_bf16(vf, pf, acc[mt], 0, 0, 0);
      }
    }
    __syncthreads();
  }
  const int b = bh >> 4, h = bh & 15;
  const float inv = 1.f / l_run;
  const long obase = ((long)(b * 1024 + qrow)) * 1024 + h * 64;
#pragma unroll
  for (int mt = 0; mt < 4; ++mt) {
    const long o = obase + mt * 16 + lg * 4;
    *(uint32_t*)&Out[o] =
        (uint32_t)f2bf(acc[mt][0] * inv) | ((uint32_t)f2bf(acc[mt][1] * inv) << 16);
    *(uint32_t*)&Out[o + 2] =
        (uint32_t)f2bf(acc[mt][2] * inv) | ((uint32_t)f2bf(acc[mt][3] * inv) << 16);
  }
}

extern "C" void kernel_launch(void* const* d_in, const int* in_sizes, int n_in,
                              void* d_out, int out_size, void* d_ws, size_t ws_size,
                              hipStream_t stream) {
  const float* x     = (const float*)d_in[0];
  const float* rope  = (const float*)d_in[1];
  const float* dte   = (const float*)d_in[2];
  const float* vres  = (const float*)d_in[3];
  const float* Wqkv  = (const float*)d_in[4];
  const float* bqkv  = (const float*)d_in[5];
  const float* Wdt   = (const float*)d_in[6];
  const float* bdt   = (const float*)d_in[7];
  const float* qn_g  = (const float*)d_in[8];
  const float* qn_b  = (const float*)d_in[9];
  const float* kn_g  = (const float*)d_in[10];
  const float* kn_b  = (const float*)d_in[11];
  const float* l1    = (const float*)d_in[12];
  const float* l2    = (const float*)d_in[13];
  const float* Wproj = (const float*)d_in[14];
  const float* bproj = (const float*)d_in[15];
  float* out = (float*)d_out;

  char* ws = (char*)d_ws;
  u16*   A_cat = (u16*)(ws);                    // [4096,2048] bf16
  u16*   W_cat = (u16*)(ws + 16777216);         // [3072,2048] bf16
  u16*   Wp    = (u16*)(ws + 29360128);         // [1024,1024] bf16
  float* qkv   = (float*)(ws + 31457280);       // [4096,3072] fp32
  u16*   Qb    = (u16*)(ws + 81788928);         // [64,1024,64] bf16
  u16*   Ksw   = (u16*)(ws + 90177536);         // swizzled K
  u16*   VTsw  = (u16*)(ws + 98566144);         // swizzled V^T
  u16*   AO    = (u16*)(ws + 106954752);        // [4096,1024] bf16

  cvt_cat_bf16<<<2048, 256, 0, stream>>>(x, dte, A_cat, (long)4096 * 2048);
  cvt_cat_bf16<<<2048, 256, 0, stream>>>(Wqkv, Wdt, W_cat, (long)3072 * 2048);
  cvt_bf16<<<1024, 256, 0, stream>>>(Wproj, Wp, (long)1024 * 1024);
  // QKV+dt fused GEMM on the 256^2 pipelined kernel: grid 16x12 = 192 blocks
  gemm256<<<192, 512, 0, stream>>>(A_cat, W_cat, qkv, bqkv, bdt, 4096, 3072, 2048);
  fuse_qkv2<<<dim3(64, 16), 256, 0, stream>>>(qkv, vres, rope, qn_g, qn_b, kn_g, kn_b,
                                              l1, l2, Qb, Ksw, VTsw);
  attn_fwd2<<<dim3(64, 16), 256, 0, stream>>>(Qb, Ksw, VTsw, AO);
  gemm_bt<<<dim3(32, 8), 256, 0, stream>>>(AO, Wp, out, bproj, nullptr, 4096, 1024, 1024);
}

// Round 4
// 173.044 us; speedup vs baseline: 1.0034x; 1.0034x over previous
//
#include <hip/hip_runtime.h>
#include <stdint.h>

typedef unsigned short u16;
typedef __attribute__((ext_vector_type(8))) short short8;
typedef __attribute__((ext_vector_type(4))) float f32x4;
typedef __attribute__((ext_vector_type(4))) unsigned short u16x4;

#define DEVI __device__ __forceinline__

DEVI u16 f2bf(float f) {
  uint32_t u = __builtin_bit_cast(uint32_t, f);
  u += 0x7fffu + ((u >> 16) & 1u);
  return (u16)(u >> 16);
}

DEVI void gload_lds16(const void* g, void* l) {
  __builtin_amdgcn_global_load_lds(
      (const __attribute__((address_space(1))) void*)g,
      (__attribute__((address_space(3))) void*)(uint32_t)(uintptr_t)l,
      16, 0, 0);
}

// ---------------- convert / concat fp32 -> bf16 ----------------
__global__ void cvt_cat_bf16(const float* __restrict__ a, const float* __restrict__ b,
                             u16* __restrict__ dst, long total) {
  for (long i = ((long)blockIdx.x * 256 + threadIdx.x) * 4; i < total;
       i += (long)gridDim.x * 1024) {
    const long row = i >> 11;
    const long c = i & 2047;
    const float* src = (c < 1024) ? (a + row * 1024 + c) : (b + row * 1024 + (c - 1024));
    const float4 v = *(const float4*)src;
    u16x4 o = {f2bf(v.x), f2bf(v.y), f2bf(v.z), f2bf(v.w)};
    *(u16x4*)(dst + i) = o;
  }
}

__global__ void cvt_bf16(const float* __restrict__ a, u16* __restrict__ dst, long total) {
  for (long i = ((long)blockIdx.x * 256 + threadIdx.x) * 4; i < total;
       i += (long)gridDim.x * 1024) {
    const float4 v = *(const float4*)(a + i);
    u16x4 o = {f2bf(v.x), f2bf(v.y), f2bf(v.z), f2bf(v.w)};
    *(u16x4*)(dst + i) = o;
  }
}

// ---------------- bf16 GEMM 128^2 (m97 structure) — used for proj ----------------
__global__ __launch_bounds__(256, 2)
void gemm_bt(const u16* __restrict__ A, const u16* __restrict__ B,
             float* __restrict__ C, const float* __restrict__ bias1,
             const float* __restrict__ bias2, int M, int N, int K) {
  __shared__ u16 As[128 * 32];
  __shared__ u16 Bs[128 * 32];
  const int t = threadIdx.x;
  const int w = t >> 6, l = t & 63;
  const int l15 = l & 15, lg = l >> 4;
  const int bm = blockIdx.x, bn = blockIdx.y;
  const int wr = (w >> 1) * 64, wc = (w & 1) * 64;
  f32x4 acc[4][4] = {};
  const int c0 = w * 64 + l;

  for (int kt = 0; kt < (K >> 5); ++kt) {
#pragma unroll
    for (int i = 0; i < 2; ++i) {
      const int c = i * 256 + c0;
      const int row = c >> 2, seg = c & 3;
      gload_lds16(A + (long)(bm * 128 + row) * K + kt * 32 + seg * 8,
                  (char*)As + w * 1024 + i * 4096);
      gload_lds16(B + (long)(bn * 128 + row) * K + kt * 32 + seg * 8,
                  (char*)Bs + w * 1024 + i * 4096);
    }
    __syncthreads();
    short8 af[4], bfr[4];
#pragma unroll
    for (int m = 0; m < 4; ++m)
      af[m] = *(const short8*)&As[(wr + m * 16 + l15) * 32 + lg * 8];
#pragma unroll
    for (int n = 0; n < 4; ++n)
      bfr[n] = *(const short8*)&Bs[(wc + n * 16 + l15) * 32 + lg * 8];
#pragma unroll
    for (int m = 0; m < 4; ++m)
#pragma unroll
      for (int n = 0; n < 4; ++n)
        acc[m][n] = __builtin_amdgcn_mfma_f32_16x16x32_bf16(af[m], bfr[n], acc[m][n], 0, 0, 0);
    __syncthreads();
  }
#pragma unroll
  for (int m = 0; m < 4; ++m) {
    const int row0 = bm * 128 + wr + m * 16 + lg * 4;
#pragma unroll
    for (int n = 0; n < 4; ++n) {
      const int col = bn * 128 + wc + n * 16 + l15;
      float bia = 0.f;
      if (bias1) bia += bias1[col];
      if (bias2) bia += bias2[col];
#pragma unroll
      for (int r = 0; r < 4; ++r)
        C[(long)(row0 + r) * N + col] = acc[m][n][r] + bia;
    }
  }
}

// ---------------- bf16 GEMM 256^2, 8 waves, phase-structured (m201 style) -------
// A [M,K], B [N,K] bf16 row-major; C [M,N] fp32 + bias. M%256==0, N%256==0,
// K%32==0, K/32 >= 4. 4 LDS tile-buffers; staging for tile t+3 goes to
// buf[(t+3)&3] == buf[(t-1)&3], freed one full tile (4 barriers) earlier.
// Per tile: 2 phases x {8/4 ds_read -> stage -> barrier -> lgkmcnt(0) ->
// 16 MFMA -> barrier}; one counted vmcnt(8) per tile, never 0 in main loop.
// LDS swizzle: logical (row r, granule g) at physical row r>>1,
// slot (g+4*(r&1))^((r>>1)&7): every ds_read_b128 is 2-way (free).
__global__ __launch_bounds__(512, 2)
void gemm256(const u16* __restrict__ A, const u16* __restrict__ B,
             float* __restrict__ C, const float* __restrict__ bias1,
             const float* __restrict__ bias2, int M, int N, int K) {
  __shared__ u16 lds[4][16384];  // 4 bufs x (A 256x32 | B 256x32) = 128 KiB
  const int t = threadIdx.x;
  const int w = t >> 6, l = t & 63;
  const int l15 = l & 15, lg = l >> 4;
  const int wr = w >> 2, wc = w & 3;  // 2 x 4 wave grid -> 128 x 64 per wave
  const int nbn = N >> 8;
  const int nb = gridDim.x;
  const int bid = blockIdx.x;
  const int lid = ((nb & 7) == 0) ? ((bid & 7) * (nb >> 3) + (bid >> 3)) : bid;
  const int bm = lid / nbn, bn = lid % nbn;
  const long rowA0 = (long)bm * 256;
  const long rowB0 = (long)bn * 256;
  const int nkt = K >> 5;

  // staging geometry: lane l, issue i writes physical row i*64+w*8+(l>>3), slot l&7
  const int su = (l & 7) ^ (l >> 3);
  const int rsub = 2 * (l >> 3) + (su >> 2);
  const int sg = su & 3;
  // fragment-read slot: logical row = base + l15, granule = lg
  const int sfr = (lg + 4 * (l15 & 1)) ^ (l15 >> 1);

  f32x4 acc[8][4] = {};

#define STAGE_A(KT)                                                            \
  {                                                                            \
    const int _b = (KT) & 3;                                                   \
    _Pragma("unroll") for (int i = 0; i < 2; ++i) {                            \
      const int r = i * 128 + w * 16 + rsub;                                   \
      gload_lds16(A + (rowA0 + r) * K + (KT) * 32 + sg * 8,                    \
                  (char*)&lds[_b][(i * 64 + w * 8) * 64]);                     \
    }                                                                          \
  }
#define STAGE_B(KT)                                                            \
  {                                                                            \
    const int _b = (KT) & 3;                                                   \
    _Pragma("unroll") for (int i = 0; i < 2; ++i) {                            \
      const int r = i * 128 + w * 16 + rsub;                                   \
      gload_lds16(B + (rowB0 + r) * K + (KT) * 32 + sg * 8,                    \
                  (char*)&lds[_b][8192 + (i * 64 + w * 8) * 64]);              \
    }                                                                          \
  }

#define TILE(KT, DO_STAGE, DO_VM, JSTR)                                        \
  {                                                                            \
    const u16* bufp = lds[(KT) & 3];                                           \
    /* ---- phase 0: reads, stage, bar, lgkm0, 16 MFMA, bar ---- */            \
    short8 bfr[4], alo[4];                                                     \
    _Pragma("unroll") for (int n = 0; n < 4; ++n) {                            \
      const int p = wc * 32 + n * 8 + (l15 >> 1);                              \
      bfr[n] = *(const short8*)&bufp[8192 + p * 64 + sfr * 8];                 \
    }                                                                          \
    _Pragma("unroll") for (int m = 0; m < 4; ++m) {                            \
      const int p = wr * 64 + m * 8 + (l15 >> 1);                              \
      alo[m] = *(const short8*)&bufp[p * 64 + sfr * 8];                        \
    }                                                                          \
    if (DO_STAGE) STAGE_A((KT) + 3);                                           \
    __builtin_amdgcn_sched_barrier(0);                                         \
    __builtin_amdgcn_s_barrier();                                              \
    asm volatile("s_waitcnt lgkmcnt(0)" ::: "memory");                         \
    __builtin_amdgcn_sched_barrier(0);                                         \
    __builtin_amdgcn_s_setprio(1);                                             \
    _Pragma("unroll") for (int m = 0; m < 4; ++m)                              \
      _Pragma("unroll") for (int n = 0; n < 4; ++n)                            \
        acc[m][n] = __builtin_amdgcn_mfma_f32_16x16x32_bf16(alo[m], bfr[n],    \
                                                            acc[m][n], 0, 0, 0); \
    __builtin_amdgcn_s_setprio(0);                                             \
    __builtin_amdgcn_sched_barrier(0);                                         \
    __builtin_amdgcn_s_barrier();                                              \
    /* ---- phase 1: reads, stage, vmcnt, bar, lgkm0, 16 MFMA, bar ---- */     \
    short8 ahi[4];                                                             \
    _Pragma("unroll") for (int m = 0; m < 4; ++m) {                            \
      const int p = wr * 64 + (m + 4) * 8 + (l15 >> 1);                        \
      ahi[m] = *(const short8*)&bufp[p * 64 + sfr * 8];                        \
    }                                                                          \
    if (DO_STAGE) STAGE_B((KT) + 3);                                           \
    __builtin_amdgcn_sched_barrier(0);                                         \
    __builtin_amdgcn_s_barrier();                                              \
    asm volatile("s_waitcnt lgkmcnt(0)" ::: "memory");                         \
    __builtin_amdgcn_sched_barrier(0);                                         \
    __builtin_amdgcn_s_setprio(1);                                             \
    _Pragma("unroll") for (int m = 0; m < 4; ++m)                              \
      _Pragma("unroll") for (int n = 0; n < 4; ++n)                            \
        acc[m + 4][n] = __builtin_amdgcn_mfma_f32_16x16x32_bf16(               \
            ahi[m], bfr[n], acc[m + 4][n], 0, 0, 0);                           \
    __builtin_amdgcn_s_setprio(0);                                             \
    if (DO_VM) asm volatile("s_waitcnt vmcnt(" JSTR ")" ::: "memory");         \
    __builtin_amdgcn_sched_barrier(0);                                         \
    __builtin_amdgcn_s_barrier();                                              \
  }

  // prologue: stage tiles 0,1,2 (12 loads in flight)
  STAGE_A(0); STAGE_B(0);
  STAGE_A(1); STAGE_B(1);
  STAGE_A(2); STAGE_B(2);
  asm volatile("s_waitcnt vmcnt(8)" ::: "memory");  // tile 0 landed (mine)
  __builtin_amdgcn_s_barrier();                     // ... and everyone's

  for (int kt = 0; kt < nkt - 3; ++kt) TILE(kt, 1, 1, "8")
  TILE(nkt - 3, 0, 1, "4")
  TILE(nkt - 2, 0, 1, "0")
  TILE(nkt - 1, 0, 0, "0")
#undef TILE
#undef STAGE_A
#undef STAGE_B

  // C write + bias
#pragma unroll
  for (int m = 0; m < 8; ++m) {
    const int row0 = bm * 256 + wr * 128 + m * 16 + lg * 4;
#pragma unroll
    for (int n = 0; n < 4; ++n) {
      const int col = bn * 256 + wc * 64 + n * 16 + l15;
      float bia = 0.f;
      if (bias1) bia += bias1[col];
      if (bias2) bia += bias2[col];
#pragma unroll
      for (int r = 0; r < 4; ++r)
        C[(long)(row0 + r) * N + col] = acc[m][n][r] + bia;
    }
  }
}

// ---------------- fuse: split qkv, vres mix, LN(q,k), RoPE ----------------
__global__ __launch_bounds__(256)
void fuse_qkv2(const float* __restrict__ qkv, const float* __restrict__ vres,
               const float* __restrict__ rope,
               const float* __restrict__ qg, const float* __restrict__ qb,
               const float* __restrict__ kg, const float* __restrict__ kb,
               const float* __restrict__ pl1, const float* __restrict__ pl2,
               u16* __restrict__ Q, u16* __restrict__ Ksw, u16* __restrict__ VTsw) {
  __shared__ u16 Vl[64][72];
  const int t = threadIdx.x, w = t >> 6, d = t & 63;
  const int bh = blockIdx.x, ntile = blockIdx.y;
  const int b = bh >> 4, h = bh & 15, n0 = ntile * 64;
  const float l1 = pl1[0], l2 = pl2[0];
  const float gq = qg[d], bq = qb[d];
  const float gk = kg[d], bk = kb[d];
  const float sgn = (d < 32) ? -1.f : 1.f;
  const int c = d >> 3, d7 = d & 7;

  for (int i = 0; i < 16; ++i) {
    const int nl = w * 16 + i;
    const int n = n0 + nl;
    const long base = ((long)(b * 1024 + n)) * 3072 + h * 64 + d;
    float q = qkv[base];
    float k = qkv[base + 1024];
    float v = qkv[base + 2048];
    v = l1 * v + l2 * vres[((long)(bh * 1024 + n)) * 64 + d];
    const float sinv = rope[n * 128 + d];
    const float cosv = rope[n * 128 + 64 + d];
    float s = q;
#pragma unroll
    for (int off = 1; off < 64; off <<= 1) s += __shfl_xor(s, off);
    const float qc = q - s * (1.f / 64.f);
    float vs = qc * qc;
#pragma unroll
    for (int off = 1; off < 64; off <<= 1) vs += __shfl_xor(vs, off);
    const float qn = qc * (1.f / sqrtf(vs * (1.f / 64.f) + 1e-5f)) * gq + bq;
    float s2 = k;
#pragma unroll
    for (int off = 1; off < 64; off <<= 1) s2 += __shfl_xor(s2, off);
    const float kc = k - s2 * (1.f / 64.f);
    float vs2 = kc * kc;
#pragma unroll
    for (int off = 1; off < 64; off <<= 1) vs2 += __shfl_xor(vs2, off);
    const float kn = kc * (1.f / sqrtf(vs2 * (1.f / 64.f) + 1e-5f)) * gk + bk;
    const float qo = __shfl_xor(qn, 32);
    const float ko = __shfl_xor(kn, 32);
    const float qr = qn * cosv + sgn * qo * sinv;
    const float kr = kn * cosv + sgn * ko * sinv;
    Q[(long)bh * 65536 + (long)n * 64 + d] = f2bf(qr);
    Ksw[(long)bh * 65536 + (long)n * 64 + ((c ^ (n & 7)) * 8 + d7)] = f2bf(kr);
    Vl[nl][d] = f2bf(v);
  }
  __syncthreads();
#pragma unroll
  for (int i = 0; i < 2; ++i) {
    const int task = i * 256 + t;
    const int dd = task >> 3, cc = task & 7;
    short8 o;
#pragma unroll
    for (int u = 0; u < 8; ++u) o[u] = (short)Vl[cc * 8 + u][dd];
    *(short8*)&VTsw[((long)(bh * 64 + dd)) * 1024 + n0 + ((cc ^ (dd & 7)) * 8)] = o;
  }
}

// ---------------- flash attention fwd: swapped QK^T and PV ----------------
__global__ __launch_bounds__(256, 4)
void attn_fwd2(const u16* __restrict__ Q, const u16* __restrict__ Ksw,
               const u16* __restrict__ VTsw, u16* __restrict__ Out) {
  __shared__ u16 Kl[64 * 64];
  __shared__ u16 Vl[64 * 64];
  __shared__ u16 Pl[4][16 * 64];
  const int t = threadIdx.x, w = t >> 6, l = t & 63;
  const int l15 = l & 15, lg = l >> 4;
  const int x7 = l15 & 7;
  const int bh = blockIdx.x, q0 = blockIdx.y * 64;
  const long bo = (long)bh * 65536;
  u16* Plw = &Pl[w][0];

  const int qrow = q0 + w * 16 + l15;
  short8 qf[2];
#pragma unroll
  for (int ks = 0; ks < 2; ++ks)
    qf[ks] = *(const short8*)&Q[bo + (long)qrow * 64 + ks * 32 + lg * 8];

  f32x4 acc[4] = {};
  float m_run = -1e30f, l_run = 0.f;

  for (int kv = 0; kv < 16; ++kv) {
    const int kvb = kv * 64;
#pragma unroll
    for (int i = 0; i < 2; ++i) {
      const int idx = i * 256 + t;
      const int row = idx >> 3, seg = idx & 7;
      gload_lds16(Ksw + bo + (long)(kvb + row) * 64 + seg * 8, (char*)Kl + idx * 16);
      gload_lds16(VTsw + bo + (long)row * 1024 + kvb + seg * 8, (char*)Vl + idx * 16);
    }
    __syncthreads();
    f32x4 p[4];
#pragma unroll
    for (int mt = 0; mt < 4; ++mt) {
      f32x4 ps = {};
#pragma unroll
      for (int ks = 0; ks < 2; ++ks) {
        const short8 kf =
            *(const short8*)&Kl[(mt * 16 + l15) * 64 + (((ks * 4 + lg) ^ x7) * 8)];
        ps = __builtin_amdgcn_mfma_f32_16x16x32_bf16(kf, qf[ks], ps, 0, 0, 0);
      }
      p[mt] = ps;
    }
    float mx = p[0][0];
#pragma unroll
    for (int mt = 0; mt < 4; ++mt)
#pragma unroll
      for (int r = 0; r < 4; ++r) mx = fmaxf(mx, p[mt][r]);
    mx = fmaxf(mx, __shfl_xor(mx, 16));
    mx = fmaxf(mx, __shfl_xor(mx, 32));
    const float mnew = fmaxf(m_run, mx * 0.125f);
    const float alpha = __expf(m_run - mnew);
    m_run = mnew;
    float sum = 0.f;
#pragma unroll
    for (int mt = 0; mt < 4; ++mt)
#pragma unroll
      for (int r = 0; r < 4; ++r) {
        const float e = __expf(p[mt][r] * 0.125f - mnew);
        p[mt][r] = e;
        sum += e;
      }
    sum += __shfl_xor(sum, 16);
    sum += __shfl_xor(sum, 32);
    l_run = l_run * alpha + sum;
#pragma unroll
    for (int mt = 0; mt < 4; ++mt) {
      const int c = mt * 2 + (lg >> 1);
      char* bp = (char*)Plw + l15 * 128 + ((c ^ x7) * 16) + (lg & 1) * 8;
      *(uint32_t*)bp = (uint32_t)f2bf(p[mt][0]) | ((uint32_t)f2bf(p[mt][1]) << 16);
      *(uint32_t*)(bp + 4) = (uint32_t)f2bf(p[mt][2]) | ((uint32_t)f2bf(p[mt][3]) << 16);
    }
#pragma unroll
    for (int mt = 0; mt < 4; ++mt)
#pragma unroll
      for (int r = 0; r < 4; ++r) acc[mt][r] *= alpha;
#pragma unroll
    for (int ks = 0; ks < 2; ++ks) {
      const short8 pf =
          *(const short8*)((char*)Plw + l15 * 128 + (((ks * 4 + lg) ^ x7) * 16));
#pragma unroll
      for (int mt = 0; mt < 4; ++mt) {
        const short8 vf =
            *(const short8*)&Vl[(mt * 16 + l15) * 64 + (((ks * 4 + lg) ^ x7) * 8)];
        acc[mt] = __builtin_amdgcn_mfma_f32_16x16x32_bf16(vf, pf, acc[mt], 0, 0, 0);
      }
    }
    __syncthreads();
  }
  const int b = bh >> 4, h = bh & 15;
  const float inv = 1.f / l_run;
  const long obase = ((long)(b * 1024 + qrow)) * 1024 + h * 64;
#pragma unroll
  for (int mt = 0; mt < 4; ++mt) {
    const long o = obase + mt * 16 + lg * 4;
    *(uint32_t*)&Out[o] =
        (uint32_t)f2bf(acc[mt][0] * inv) | ((uint32_t)f2bf(acc[mt][1] * inv) << 16);
    *(uint32_t*)&Out[o + 2] =
        (uint32_t)f2bf(acc[mt][2] * inv) | ((uint32_t)f2bf(acc[mt][3] * inv) << 16);
  }
}

extern "C" void kernel_launch(void* const* d_in, const int* in_sizes, int n_in,
                              void* d_out, int out_size, void* d_ws, size_t ws_size,
                              hipStream_t stream) {
  const float* x     = (const float*)d_in[0];
  const float* rope  = (const float*)d_in[1];
  const float* dte   = (const float*)d_in[2];
  const float* vres  = (const float*)d_in[3];
  const float* Wqkv  = (const float*)d_in[4];
  const float* bqkv  = (const float*)d_in[5];
  const float* Wdt   = (const float*)d_in[6];
  const float* bdt   = (const float*)d_in[7];
  const float* qn_g  = (const float*)d_in[8];
  const float* qn_b  = (const float*)d_in[9];
  const float* kn_g  = (const float*)d_in[10];
  const float* kn_b  = (const float*)d_in[11];
  const float* l1    = (const float*)d_in[12];
  const float* l2    = (const float*)d_in[13];
  const float* Wproj = (const float*)d_in[14];
  const float* bproj = (const float*)d_in[15];
  float* out = (float*)d_out;

  char* ws = (char*)d_ws;
  u16*   A_cat = (u16*)(ws);                    // [4096,2048] bf16
  u16*   W_cat = (u16*)(ws + 16777216);         // [3072,2048] bf16
  u16*   Wp    = (u16*)(ws + 29360128);         // [1024,1024] bf16
  float* qkv   = (float*)(ws + 31457280);       // [4096,3072] fp32
  u16*   Qb    = (u16*)(ws + 81788928);         // [64,1024,64] bf16
  u16*   Ksw   = (u16*)(ws + 90177536);         // swizzled K
  u16*   VTsw  = (u16*)(ws + 98566144);         // swizzled V^T
  u16*   AO    = (u16*)(ws + 106954752);        // [4096,1024] bf16

  cvt_cat_bf16<<<2048, 256, 0, stream>>>(x, dte, A_cat, (long)4096 * 2048);
  cvt_cat_bf16<<<2048, 256, 0, stream>>>(Wqkv, Wdt, W_cat, (long)3072 * 2048);
  cvt_bf16<<<1024, 256, 0, stream>>>(Wproj, Wp, (long)1024 * 1024);
  // QKV+dt fused GEMM on the 256^2 phase-structured kernel: 16x12 = 192 blocks
  gemm256<<<192, 512, 0, stream>>>(A_cat, W_cat, qkv, bqkv, bdt, 4096, 3072, 2048);
  fuse_qkv2<<<dim3(64, 16), 256, 0, stream>>>(qkv, vres, rope, qn_g, qn_b, kn_g, kn_b,
                                              l1, l2, Qb, Ksw, VTsw);
  attn_fwd2<<<dim3(64, 16), 256, 0, stream>>>(Qb, Ksw, VTsw, AO);
  gemm_bt<<<dim3(32, 8), 256, 0, stream>>>(AO, Wp, out, bproj, nullptr, 4096, 1024, 1024);
}

// Round 5
// 171.057 us; speedup vs baseline: 1.0150x; 1.0116x over previous
//
#include <hip/hip_runtime.h>
#include <stdint.h>

typedef unsigned short u16;
typedef __attribute__((ext_vector_type(8))) short short8;
typedef __attribute__((ext_vector_type(4))) float f32x4;
typedef __attribute__((ext_vector_type(4))) unsigned short u16x4;

#define DEVI __device__ __forceinline__

DEVI u16 f2bf(float f) {
  uint32_t u = __builtin_bit_cast(uint32_t, f);
  u += 0x7fffu + ((u >> 16) & 1u);
  return (u16)(u >> 16);
}

DEVI float bf2f(u16 u) {
  uint32_t v = ((uint32_t)u) << 16;
  return __builtin_bit_cast(float, v);
}

DEVI void gload_lds16(const void* g, void* l) {
  __builtin_amdgcn_global_load_lds(
      (const __attribute__((address_space(1))) void*)g,
      (__attribute__((address_space(3))) void*)(uint32_t)(uintptr_t)l,
      16, 0, 0);
}

// ---------------- convert / concat fp32 -> bf16 ----------------
__global__ void cvt_cat_bf16(const float* __restrict__ a, const float* __restrict__ b,
                             u16* __restrict__ dst, long total) {
  for (long i = ((long)blockIdx.x * 256 + threadIdx.x) * 4; i < total;
       i += (long)gridDim.x * 1024) {
    const long row = i >> 11;
    const long c = i & 2047;
    const float* src = (c < 1024) ? (a + row * 1024 + c) : (b + row * 1024 + (c - 1024));
    const float4 v = *(const float4*)src;
    u16x4 o = {f2bf(v.x), f2bf(v.y), f2bf(v.z), f2bf(v.w)};
    *(u16x4*)(dst + i) = o;
  }
}

__global__ void cvt_bf16(const float* __restrict__ a, u16* __restrict__ dst, long total) {
  for (long i = ((long)blockIdx.x * 256 + threadIdx.x) * 4; i < total;
       i += (long)gridDim.x * 1024) {
    const float4 v = *(const float4*)(a + i);
    u16x4 o = {f2bf(v.x), f2bf(v.y), f2bf(v.z), f2bf(v.w)};
    *(u16x4*)(dst + i) = o;
  }
}

// ---------------- bf16 GEMM 128^2 (m97 structure) — used for proj ----------------
__global__ __launch_bounds__(256, 2)
void gemm_bt(const u16* __restrict__ A, const u16* __restrict__ B,
             float* __restrict__ C, const float* __restrict__ bias1,
             const float* __restrict__ bias2, int M, int N, int K) {
  __shared__ u16 As[128 * 32];
  __shared__ u16 Bs[128 * 32];
  const int t = threadIdx.x;
  const int w = t >> 6, l = t & 63;
  const int l15 = l & 15, lg = l >> 4;
  const int bm = blockIdx.x, bn = blockIdx.y;
  const int wr = (w >> 1) * 64, wc = (w & 1) * 64;
  f32x4 acc[4][4] = {};
  const int c0 = w * 64 + l;

  for (int kt = 0; kt < (K >> 5); ++kt) {
#pragma unroll
    for (int i = 0; i < 2; ++i) {
      const int c = i * 256 + c0;
      const int row = c >> 2, seg = c & 3;
      gload_lds16(A + (long)(bm * 128 + row) * K + kt * 32 + seg * 8,
                  (char*)As + w * 1024 + i * 4096);
      gload_lds16(B + (long)(bn * 128 + row) * K + kt * 32 + seg * 8,
                  (char*)Bs + w * 1024 + i * 4096);
    }
    __syncthreads();
    short8 af[4], bfr[4];
#pragma unroll
    for (int m = 0; m < 4; ++m)
      af[m] = *(const short8*)&As[(wr + m * 16 + l15) * 32 + lg * 8];
#pragma unroll
    for (int n = 0; n < 4; ++n)
      bfr[n] = *(const short8*)&Bs[(wc + n * 16 + l15) * 32 + lg * 8];
#pragma unroll
    for (int m = 0; m < 4; ++m)
#pragma unroll
      for (int n = 0; n < 4; ++n)
        acc[m][n] = __builtin_amdgcn_mfma_f32_16x16x32_bf16(af[m], bfr[n], acc[m][n], 0, 0, 0);
    __syncthreads();
  }
#pragma unroll
  for (int m = 0; m < 4; ++m) {
    const int row0 = bm * 128 + wr + m * 16 + lg * 4;
#pragma unroll
    for (int n = 0; n < 4; ++n) {
      const int col = bn * 128 + wc + n * 16 + l15;
      float bia = 0.f;
      if (bias1) bia += bias1[col];
      if (bias2) bia += bias2[col];
#pragma unroll
      for (int r = 0; r < 4; ++r)
        C[(long)(row0 + r) * N + col] = acc[m][n][r] + bia;
    }
  }
}

// ---------------- bf16 GEMM 256^2, derived-waits read-ahead pipeline ----------
// A [M,K], B [N,K] bf16 row-major; out = bf16 Cb [M,N] (+bias). M%256==0,
// N%256==0, K%32==0, (K/32)>=6 and even. 4 LDS tile buffers, BK=32.
// Read-ahead: each phase issues the NEXT phase's ds_reads; derived counted
// lgkmcnt releases when only the current phase's operands are complete, so
// the new reads execute in the LDS pipe UNDER the MFMA cluster (m201/m232
// "derived-waits"). One counted vmcnt(6) per tile; never 0 in main loop.
// Swizzle: logical (row r, granule g) -> physical row r>>1, slot
// (g+4*(r&1))^((r>>1)&7); every ds_read_b128 lands 2-way/bank (free).
__global__ __launch_bounds__(512, 2)
void gemm256(const u16* __restrict__ A, const u16* __restrict__ B,
             u16* __restrict__ Cb, const float* __restrict__ bias1,
             const float* __restrict__ bias2, int M, int N, int K) {
  __shared__ u16 lds[4][16384];  // 4 bufs x (A 256x32 | B 256x32) = 128 KiB
  const int t = threadIdx.x;
  const int w = t >> 6, l = t & 63;
  const int l15 = l & 15, lg = l >> 4;
  const int wr = w >> 2, wc = w & 3;  // 2 x 4 wave grid -> 128 x 64 per wave
  const int nbn = N >> 8;
  const int nb = gridDim.x;
  const int bid = blockIdx.x;
  const int lid = ((nb & 7) == 0) ? ((bid & 7) * (nb >> 3) + (bid >> 3)) : bid;
  const int bm = lid / nbn, bn = lid % nbn;
  const long rowA0 = (long)bm * 256;
  const long rowB0 = (long)bn * 256;
  const int nkt = K >> 5;

  // staging geometry: lane l, issue i writes physical row i*64+w*8+(l>>3), slot l&7
  const int su = (l & 7) ^ (l >> 3);
  const int rsub = 2 * (l >> 3) + (su >> 2);
  const int sg = su & 3;
  // fragment-read slot: logical row = base + l15, granule = lg
  const int sfr = (lg + 4 * (l15 & 1)) ^ (l15 >> 1);

  f32x4 acc[8][4] = {};
  short8 alo[4], ahi[4], b0[4], b1[4];

#define STAGE_A(KT)                                                           \
  {                                                                           \
    const int _b = (KT) & 3;                                                  \
    _Pragma("unroll") for (int i = 0; i < 2; ++i) {                           \
      const int r = i * 128 + w * 16 + rsub;                                  \
      gload_lds16(A + (rowA0 + r) * K + (KT) * 32 + sg * 8,                   \
                  (char*)&lds[_b][(i * 64 + w * 8) * 64]);                    \
    }                                                                         \
  }
#define STAGE_B(KT)                                                           \
  {                                                                           \
    const int _b = (KT) & 3;                                                  \
    _Pragma("unroll") for (int i = 0; i < 2; ++i) {                           \
      const int r = i * 128 + w * 16 + rsub;                                  \
      gload_lds16(B + (rowB0 + r) * K + (KT) * 32 + sg * 8,                   \
                  (char*)&lds[_b][8192 + (i * 64 + w * 8) * 64]);             \
    }                                                                         \
  }

  // TILE: BC = current-tile B fragments, BN_ = next-tile B fragments.
#define TILE(KT, BC, BN_, VM, LG1, DO_STAGE, DO_NEXT)                         \
  {                                                                           \
    const u16* bufp = lds[(KT) & 3];                                          \
    /* PH0: issue ahi_t (next phase's A-frags); stage; derived waits */       \
    _Pragma("unroll") for (int m = 0; m < 4; ++m) {                           \
      const int p = wr * 64 + (m + 4) * 8 + (l15 >> 1);                       \
      ahi[m] = *(const short8*)&bufp[p * 64 + sfr * 8];                       \
    }                                                                         \
    if (DO_STAGE) STAGE_A((KT) + 3);                                          \
    asm volatile("s_waitcnt vmcnt(" VM ")" ::: "memory");                     \
    __builtin_amdgcn_sched_barrier(0);                                        \
    __builtin_amdgcn_s_barrier();                                             \
    asm volatile("s_waitcnt lgkmcnt(4)" ::: "memory");                        \
    __builtin_amdgcn_sched_barrier(0);                                        \
    __builtin_amdgcn_s_setprio(1);                                            \
    _Pragma("unroll") for (int m = 0; m < 4; ++m)                             \
      _Pragma("unroll") for (int n = 0; n < 4; ++n)                           \
        acc[m][n] = __builtin_amdgcn_mfma_f32_16x16x32_bf16(alo[m], BC[n],    \
                                                            acc[m][n], 0, 0, 0); \
    __builtin_amdgcn_s_setprio(0);                                            \
    __builtin_amdgcn_sched_barrier(0);                                        \
    __builtin_amdgcn_s_barrier();                                             \
    /* PH1: issue next tile's alo/bfr; stage; derived waits */                \
    if (DO_NEXT) {                                                            \
      const u16* bnp = lds[((KT) + 1) & 3];                                   \
      _Pragma("unroll") for (int m = 0; m < 4; ++m) {                         \
        const int p = wr * 64 + m * 8 + (l15 >> 1);                           \
        alo[m] = *(const short8*)&bnp[p * 64 + sfr * 8];                      \
      }                                                                       \
      _Pragma("unroll") for (int n = 0; n < 4; ++n) {                         \
        const int p = wc * 32 + n * 8 + (l15 >> 1);                           \
        BN_[n] = *(const short8*)&bnp[8192 + p * 64 + sfr * 8];               \
      }                                                                       \
    }                                                                         \
    if (DO_STAGE) STAGE_B((KT) + 3);                                          \
    __builtin_amdgcn_sched_barrier(0);                                        \
    __builtin_amdgcn_s_barrier();                                             \
    asm volatile("s_waitcnt lgkmcnt(" LG1 ")" ::: "memory");                  \
    __builtin_amdgcn_sched_barrier(0);                                        \
    __builtin_amdgcn_s_setprio(1);                                            \
    _Pragma("unroll") for (int m = 0; m < 4; ++m)                             \
      _Pragma("unroll") for (int n = 0; n < 4; ++n)                           \
        acc[m + 4][n] = __builtin_amdgcn_mfma_f32_16x16x32_bf16(              \
            ahi[m], BC[n], acc[m + 4][n], 0, 0, 0);                           \
    __builtin_amdgcn_s_setprio(0);                                            \
    __builtin_amdgcn_sched_barrier(0);                                        \
    __builtin_amdgcn_s_barrier();                                             \
  }

  // prologue: stage tiles 0,1,2; wait S(0); load tile-0 alo/bfr
  STAGE_A(0); STAGE_B(0);
  STAGE_A(1); STAGE_B(1);
  STAGE_A(2); STAGE_B(2);
  asm volatile("s_waitcnt vmcnt(8)" ::: "memory");  // S(0) landed (mine)
  __builtin_amdgcn_sched_barrier(0);
  __builtin_amdgcn_s_barrier();                     // ... and everyone's
#pragma unroll
  for (int m = 0; m < 4; ++m) {
    const int p = wr * 64 + m * 8 + (l15 >> 1);
    alo[m] = *(const short8*)&lds[0][p * 64 + sfr * 8];
  }
#pragma unroll
  for (int n = 0; n < 4; ++n) {
    const int p = wc * 32 + n * 8 + (l15 >> 1);
    b0[n] = *(const short8*)&lds[0][8192 + p * 64 + sfr * 8];
  }

  // main loop in tile pairs (b0/b1 alternate); nkt even
  for (int kt = 0; kt < nkt - 4; kt += 2) {
    TILE(kt, b0, b1, "6", "8", 1, 1)
    TILE(kt + 1, b1, b0, "6", "8", 1, 1)
  }
  TILE(nkt - 4, b0, b1, "6", "8", 1, 1)   // stages S(nkt-1)
  TILE(nkt - 3, b1, b0, "4", "8", 0, 1)
  TILE(nkt - 2, b0, b1, "0", "8", 0, 1)
  TILE(nkt - 1, b1, b0, "0", "0", 0, 0)
#undef TILE
#undef STAGE_A
#undef STAGE_B

  // C write (bf16) + bias
#pragma unroll
  for (int m = 0; m < 8; ++m) {
    const int row0 = bm * 256 + wr * 128 + m * 16 + lg * 4;
#pragma unroll
    for (int n = 0; n < 4; ++n) {
      const int col = bn * 256 + wc * 64 + n * 16 + l15;
      float bia = 0.f;
      if (bias1) bia += bias1[col];
      if (bias2) bia += bias2[col];
#pragma unroll
      for (int r = 0; r < 4; ++r)
        Cb[(long)(row0 + r) * N + col] = f2bf(acc[m][n][r] + bia);
    }
  }
}

// ---------------- fuse: split qkv (bf16), vres mix, LN(q,k), RoPE ----------------
__global__ __launch_bounds__(256)
void fuse_qkv2(const u16* __restrict__ qkv, const float* __restrict__ vres,
               const float* __restrict__ rope,
               const float* __restrict__ qg, const float* __restrict__ qb,
               const float* __restrict__ kg, const float* __restrict__ kb,
               const float* __restrict__ pl1, const float* __restrict__ pl2,
               u16* __restrict__ Q, u16* __restrict__ Ksw, u16* __restrict__ VTsw) {
  __shared__ u16 Vl[64][72];
  const int t = threadIdx.x, w = t >> 6, d = t & 63;
  const int bh = blockIdx.x, ntile = blockIdx.y;
  const int b = bh >> 4, h = bh & 15, n0 = ntile * 64;
  const float l1 = pl1[0], l2 = pl2[0];
  const float gq = qg[d], bq = qb[d];
  const float gk = kg[d], bk = kb[d];
  const float sgn = (d < 32) ? -1.f : 1.f;
  const int c = d >> 3, d7 = d & 7;

  for (int i = 0; i < 16; ++i) {
    const int nl = w * 16 + i;
    const int n = n0 + nl;
    const long base = ((long)(b * 1024 + n)) * 3072 + h * 64 + d;
    float q = bf2f(qkv[base]);
    float k = bf2f(qkv[base + 1024]);
    float v = bf2f(qkv[base + 2048]);
    v = l1 * v + l2 * vres[((long)(bh * 1024 + n)) * 64 + d];
    const float sinv = rope[n * 128 + d];
    const float cosv = rope[n * 128 + 64 + d];
    float s = q;
#pragma unroll
    for (int off = 1; off < 64; off <<= 1) s += __shfl_xor(s, off);
    const float qc = q - s * (1.f / 64.f);
    float vs = qc * qc;
#pragma unroll
    for (int off = 1; off < 64; off <<= 1) vs += __shfl_xor(vs, off);
    const float qn = qc * (1.f / sqrtf(vs * (1.f / 64.f) + 1e-5f)) * gq + bq;
    float s2 = k;
#pragma unroll
    for (int off = 1; off < 64; off <<= 1) s2 += __shfl_xor(s2, off);
    const float kc = k - s2 * (1.f / 64.f);
    float vs2 = kc * kc;
#pragma unroll
    for (int off = 1; off < 64; off <<= 1) vs2 += __shfl_xor(vs2, off);
    const float kn = kc * (1.f / sqrtf(vs2 * (1.f / 64.f) + 1e-5f)) * gk + bk;
    const float qo = __shfl_xor(qn, 32);
    const float ko = __shfl_xor(kn, 32);
    const float qr = qn * cosv + sgn * qo * sinv;
    const float kr = kn * cosv + sgn * ko * sinv;
    Q[(long)bh * 65536 + (long)n * 64 + d] = f2bf(qr);
    Ksw[(long)bh * 65536 + (long)n * 64 + ((c ^ (n & 7)) * 8 + d7)] = f2bf(kr);
    Vl[nl][d] = f2bf(v);
  }
  __syncthreads();
#pragma unroll
  for (int i = 0; i < 2; ++i) {
    const int task = i * 256 + t;
    const int dd = task >> 3, cc = task & 7;
    short8 o;
#pragma unroll
    for (int u = 0; u < 8; ++u) o[u] = (short)Vl[cc * 8 + u][dd];
    *(short8*)&VTsw[((long)(bh * 64 + dd)) * 1024 + n0 + ((cc ^ (dd & 7)) * 8)] = o;
  }
}

// ---------------- flash attention fwd: swapped QK^T and PV ----------------
__global__ __launch_bounds__(256, 4)
void attn_fwd2(const u16* __restrict__ Q, const u16* __restrict__ Ksw,
               const u16* __restrict__ VTsw, u16* __restrict__ Out) {
  __shared__ u16 Kl[64 * 64];
  __shared__ u16 Vl[64 * 64];
  __shared__ u16 Pl[4][16 * 64];
  const int t = threadIdx.x, w = t >> 6, l = t & 63;
  const int l15 = l & 15, lg = l >> 4;
  const int x7 = l15 & 7;
  const int bh = blockIdx.x, q0 = blockIdx.y * 64;
  const long bo = (long)bh * 65536;
  u16* Plw = &Pl[w][0];

  const int qrow = q0 + w * 16 + l15;
  short8 qf[2];
#pragma unroll
  for (int ks = 0; ks < 2; ++ks)
    qf[ks] = *(const short8*)&Q[bo + (long)qrow * 64 + ks * 32 + lg * 8];

  f32x4 acc[4] = {};
  float m_run = -1e30f, l_run = 0.f;

  for (int kv = 0; kv < 16; ++kv) {
    const int kvb = kv * 64;
#pragma unroll
    for (int i = 0; i < 2; ++i) {
      const int idx = i * 256 + t;
      const int row = idx >> 3, seg = idx & 7;
      gload_lds16(Ksw + bo + (long)(kvb + row) * 64 + seg * 8, (char*)Kl + idx * 16);
      gload_lds16(VTsw + bo + (long)row * 1024 + kvb + seg * 8, (char*)Vl + idx * 16);
    }
    __syncthreads();
    f32x4 p[4];
#pragma unroll
    for (int mt = 0; mt < 4; ++mt) {
      f32x4 ps = {};
#pragma unroll
      for (int ks = 0; ks < 2; ++ks) {
        const short8 kf =
            *(const short8*)&Kl[(mt * 16 + l15) * 64 + (((ks * 4 + lg) ^ x7) * 8)];
        ps = __builtin_amdgcn_mfma_f32_16x16x32_bf16(kf, qf[ks], ps, 0, 0, 0);
      }
      p[mt] = ps;
    }
    float mx = p[0][0];
#pragma unroll
    for (int mt = 0; mt < 4; ++mt)
#pragma unroll
      for (int r = 0; r < 4; ++r) mx = fmaxf(mx, p[mt][r]);
    mx = fmaxf(mx, __shfl_xor(mx, 16));
    mx = fmaxf(mx, __shfl_xor(mx, 32));
    const float mnew = fmaxf(m_run, mx * 0.125f);
    const float alpha = __expf(m_run - mnew);
    m_run = mnew;
    float sum = 0.f;
#pragma unroll
    for (int mt = 0; mt < 4; ++mt)
#pragma unroll
      for (int r = 0; r < 4; ++r) {
        const float e = __expf(p[mt][r] * 0.125f - mnew);
        p[mt][r] = e;
        sum += e;
      }
    sum += __shfl_xor(sum, 16);
    sum += __shfl_xor(sum, 32);
    l_run = l_run * alpha + sum;
#pragma unroll
    for (int mt = 0; mt < 4; ++mt) {
      const int c = mt * 2 + (lg >> 1);
      char* bp = (char*)Plw + l15 * 128 + ((c ^ x7) * 16) + (lg & 1) * 8;
      *(uint32_t*)bp = (uint32_t)f2bf(p[mt][0]) | ((uint32_t)f2bf(p[mt][1]) << 16);
      *(uint32_t*)(bp + 4) = (uint32_t)f2bf(p[mt][2]) | ((uint32_t)f2bf(p[mt][3]) << 16);
    }
#pragma unroll
    for (int mt = 0; mt < 4; ++mt)
#pragma unroll
      for (int r = 0; r < 4; ++r) acc[mt][r] *= alpha;
#pragma unroll
    for (int ks = 0; ks < 2; ++ks) {
      const short8 pf =
          *(const short8*)((char*)Plw + l15 * 128 + (((ks * 4 + lg) ^ x7) * 16));
#pragma unroll
      for (int mt = 0; mt < 4; ++mt) {
        const short8 vf =
            *(const short8*)&Vl[(mt * 16 + l15) * 64 + (((ks * 4 + lg) ^ x7) * 8)];
        acc[mt] = __builtin_amdgcn_mfma_f32_16x16x32_bf16(vf, pf, acc[mt], 0, 0, 0);
      }
    }
    __syncthreads();
  }
  const int b = bh >> 4, h = bh & 15;
  const float inv = 1.f / l_run;
  const long obase = ((long)(b * 1024 + qrow)) * 1024 + h * 64;
#pragma unroll
  for (int mt = 0; mt < 4; ++mt) {
    const long o = obase + mt * 16 + lg * 4;
    *(uint32_t*)&Out[o] =
        (uint32_t)f2bf(acc[mt][0] * inv) | ((uint32_t)f2bf(acc[mt][1] * inv) << 16);
    *(uint32_t*)&Out[o + 2] =
        (uint32_t)f2bf(acc[mt][2] * inv) | ((uint32_t)f2bf(acc[mt][3] * inv) << 16);
  }
}

extern "C" void kernel_launch(void* const* d_in, const int* in_sizes, int n_in,
                              void* d_out, int out_size, void* d_ws, size_t ws_size,
                              hipStream_t stream) {
  const float* x     = (const float*)d_in[0];
  const float* rope  = (const float*)d_in[1];
  const float* dte   = (const float*)d_in[2];
  const float* vres  = (const float*)d_in[3];
  const float* Wqkv  = (const float*)d_in[4];
  const float* bqkv  = (const float*)d_in[5];
  const float* Wdt   = (const float*)d_in[6];
  const float* bdt   = (const float*)d_in[7];
  const float* qn_g  = (const float*)d_in[8];
  const float* qn_b  = (const float*)d_in[9];
  const float* kn_g  = (const float*)d_in[10];
  const float* kn_b  = (const float*)d_in[11];
  const float* l1    = (const float*)d_in[12];
  const float* l2    = (const float*)d_in[13];
  const float* Wproj = (const float*)d_in[14];
  const float* bproj = (const float*)d_in[15];
  float* out = (float*)d_out;

  char* ws = (char*)d_ws;
  u16*   A_cat = (u16*)(ws);                    // [4096,2048] bf16
  u16*   W_cat = (u16*)(ws + 16777216);         // [3072,2048] bf16
  u16*   Wp    = (u16*)(ws + 29360128);         // [1024,1024] bf16
  u16*   qkvb  = (u16*)(ws + 31457280);         // [4096,3072] bf16
  u16*   Qb    = (u16*)(ws + 56623104);         // [64,1024,64] bf16
  u16*   Ksw   = (u16*)(ws + 65011712);         // swizzled K
  u16*   VTsw  = (u16*)(ws + 73400320);         // swizzled V^T
  u16*   AO    = (u16*)(ws + 81788928);         // [4096,1024] bf16
  // total ws usage: 90,177,536 bytes

  cvt_cat_bf16<<<2048, 256, 0, stream>>>(x, dte, A_cat, (long)4096 * 2048);
  cvt_cat_bf16<<<2048, 256, 0, stream>>>(Wqkv, Wdt, W_cat, (long)3072 * 2048);
  cvt_bf16<<<1024, 256, 0, stream>>>(Wproj, Wp, (long)1024 * 1024);
  // QKV+dt fused GEMM, 256^2 derived-waits pipeline: 16x12 = 192 blocks
  gemm256<<<192, 512, 0, stream>>>(A_cat, W_cat, qkvb, bqkv, bdt, 4096, 3072, 2048);
  fuse_qkv2<<<dim3(64, 16), 256, 0, stream>>>(qkvb, vres, rope, qn_g, qn_b, kn_g, kn_b,
                                              l1, l2, Qb, Ksw, VTsw);
  attn_fwd2<<<dim3(64, 16), 256, 0, stream>>>(Qb, Ksw, VTsw, AO);
  gemm_bt<<<dim3(32, 8), 256, 0, stream>>>(AO, Wp, out, bproj, nullptr, 4096, 1024, 1024);
}

// Round 6
// 170.814 us; speedup vs baseline: 1.0165x; 1.0014x over previous
//
#include <hip/hip_runtime.h>
#include <stdint.h>

typedef unsigned short u16;
typedef __attribute__((ext_vector_type(8))) short short8;
typedef __attribute__((ext_vector_type(4))) float f32x4;
typedef __attribute__((ext_vector_type(4))) unsigned short u16x4;

#define DEVI __device__ __forceinline__

DEVI u16 f2bf(float f) {
  uint32_t u = __builtin_bit_cast(uint32_t, f);
  u += 0x7fffu + ((u >> 16) & 1u);
  return (u16)(u >> 16);
}

DEVI float bf2f(u16 u) {
  uint32_t v = ((uint32_t)u) << 16;
  return __builtin_bit_cast(float, v);
}

DEVI void gload_lds16(const void* g, void* l) {
  __builtin_amdgcn_global_load_lds(
      (const __attribute__((address_space(1))) void*)g,
      (__attribute__((address_space(3))) void*)(uint32_t)(uintptr_t)l,
      16, 0, 0);
}

// ---------------- convert / concat fp32 -> bf16 ----------------
__global__ void cvt_cat_bf16(const float* __restrict__ a, const float* __restrict__ b,
                             u16* __restrict__ dst, long total) {
  for (long i = ((long)blockIdx.x * 256 + threadIdx.x) * 4; i < total;
       i += (long)gridDim.x * 1024) {
    const long row = i >> 11;
    const long c = i & 2047;
    const float* src = (c < 1024) ? (a + row * 1024 + c) : (b + row * 1024 + (c - 1024));
    const float4 v = *(const float4*)src;
    u16x4 o = {f2bf(v.x), f2bf(v.y), f2bf(v.z), f2bf(v.w)};
    *(u16x4*)(dst + i) = o;
  }
}

__global__ void cvt_bf16(const float* __restrict__ a, u16* __restrict__ dst, long total) {
  for (long i = ((long)blockIdx.x * 256 + threadIdx.x) * 4; i < total;
       i += (long)gridDim.x * 1024) {
    const float4 v = *(const float4*)(a + i);
    u16x4 o = {f2bf(v.x), f2bf(v.y), f2bf(v.z), f2bf(v.w)};
    *(u16x4*)(dst + i) = o;
  }
}

// ---------------- bf16 GEMM 128^2 (m97 structure), fp32 out — proj ------------
__global__ __launch_bounds__(256, 2)
void gemm_bt(const u16* __restrict__ A, const u16* __restrict__ B,
             float* __restrict__ C, const float* __restrict__ bias1,
             const float* __restrict__ bias2, int M, int N, int K) {
  __shared__ u16 As[128 * 32];
  __shared__ u16 Bs[128 * 32];
  const int t = threadIdx.x;
  const int w = t >> 6, l = t & 63;
  const int l15 = l & 15, lg = l >> 4;
  const int bm = blockIdx.x, bn = blockIdx.y;
  const int wr = (w >> 1) * 64, wc = (w & 1) * 64;
  f32x4 acc[4][4] = {};
  const int c0 = w * 64 + l;

  for (int kt = 0; kt < (K >> 5); ++kt) {
#pragma unroll
    for (int i = 0; i < 2; ++i) {
      const int c = i * 256 + c0;
      const int row = c >> 2, seg = c & 3;
      gload_lds16(A + (long)(bm * 128 + row) * K + kt * 32 + seg * 8,
                  (char*)As + w * 1024 + i * 4096);
      gload_lds16(B + (long)(bn * 128 + row) * K + kt * 32 + seg * 8,
                  (char*)Bs + w * 1024 + i * 4096);
    }
    __syncthreads();
    short8 af[4], bfr[4];
#pragma unroll
    for (int m = 0; m < 4; ++m)
      af[m] = *(const short8*)&As[(wr + m * 16 + l15) * 32 + lg * 8];
#pragma unroll
    for (int n = 0; n < 4; ++n)
      bfr[n] = *(const short8*)&Bs[(wc + n * 16 + l15) * 32 + lg * 8];
#pragma unroll
    for (int m = 0; m < 4; ++m)
#pragma unroll
      for (int n = 0; n < 4; ++n)
        acc[m][n] = __builtin_amdgcn_mfma_f32_16x16x32_bf16(af[m], bfr[n], acc[m][n], 0, 0, 0);
    __syncthreads();
  }
#pragma unroll
  for (int m = 0; m < 4; ++m) {
    const int row0 = bm * 128 + wr + m * 16 + lg * 4;
#pragma unroll
    for (int n = 0; n < 4; ++n) {
      const int col = bn * 128 + wc + n * 16 + l15;
      float bia = 0.f;
      if (bias1) bia += bias1[col];
      if (bias2) bia += bias2[col];
#pragma unroll
      for (int r = 0; r < 4; ++r)
        C[(long)(row0 + r) * N + col] = acc[m][n][r] + bia;
    }
  }
}

// ---------------- same structure, bf16 out — QKV+dt fused GEMM ----------------
__global__ __launch_bounds__(256, 2)
void gemm_bt_b16(const u16* __restrict__ A, const u16* __restrict__ B,
                 u16* __restrict__ C, const float* __restrict__ bias1,
                 const float* __restrict__ bias2, int M, int N, int K) {
  __shared__ u16 As[128 * 32];
  __shared__ u16 Bs[128 * 32];
  const int t = threadIdx.x;
  const int w = t >> 6, l = t & 63;
  const int l15 = l & 15, lg = l >> 4;
  const int bm = blockIdx.x, bn = blockIdx.y;
  const int wr = (w >> 1) * 64, wc = (w & 1) * 64;
  f32x4 acc[4][4] = {};
  const int c0 = w * 64 + l;

  for (int kt = 0; kt < (K >> 5); ++kt) {
#pragma unroll
    for (int i = 0; i < 2; ++i) {
      const int c = i * 256 + c0;
      const int row = c >> 2, seg = c & 3;
      gload_lds16(A + (long)(bm * 128 + row) * K + kt * 32 + seg * 8,
                  (char*)As + w * 1024 + i * 4096);
      gload_lds16(B + (long)(bn * 128 + row) * K + kt * 32 + seg * 8,
                  (char*)Bs + w * 1024 + i * 4096);
    }
    __syncthreads();
    short8 af[4], bfr[4];
#pragma unroll
    for (int m = 0; m < 4; ++m)
      af[m] = *(const short8*)&As[(wr + m * 16 + l15) * 32 + lg * 8];
#pragma unroll
    for (int n = 0; n < 4; ++n)
      bfr[n] = *(const short8*)&Bs[(wc + n * 16 + l15) * 32 + lg * 8];
#pragma unroll
    for (int m = 0; m < 4; ++m)
#pragma unroll
      for (int n = 0; n < 4; ++n)
        acc[m][n] = __builtin_amdgcn_mfma_f32_16x16x32_bf16(af[m], bfr[n], acc[m][n], 0, 0, 0);
    __syncthreads();
  }
#pragma unroll
  for (int m = 0; m < 4; ++m) {
    const int row0 = bm * 128 + wr + m * 16 + lg * 4;
#pragma unroll
    for (int n = 0; n < 4; ++n) {
      const int col = bn * 128 + wc + n * 16 + l15;
      float bia = 0.f;
      if (bias1) bia += bias1[col];
      if (bias2) bia += bias2[col];
#pragma unroll
      for (int r = 0; r < 4; ++r)
        C[(long)(row0 + r) * N + col] = f2bf(acc[m][n][r] + bia);
    }
  }
}

// ---------------- fuse: split qkv (bf16), vres mix, LN(q,k), RoPE ----------------
__global__ __launch_bounds__(256)
void fuse_qkv2(const u16* __restrict__ qkv, const float* __restrict__ vres,
               const float* __restrict__ rope,
               const float* __restrict__ qg, const float* __restrict__ qb,
               const float* __restrict__ kg, const float* __restrict__ kb,
               const float* __restrict__ pl1, const float* __restrict__ pl2,
               u16* __restrict__ Q, u16* __restrict__ Ksw, u16* __restrict__ VTsw) {
  __shared__ u16 Vl[64][72];
  const int t = threadIdx.x, w = t >> 6, d = t & 63;
  const int bh = blockIdx.x, ntile = blockIdx.y;
  const int b = bh >> 4, h = bh & 15, n0 = ntile * 64;
  const float l1 = pl1[0], l2 = pl2[0];
  const float gq = qg[d], bq = qb[d];
  const float gk = kg[d], bk = kb[d];
  const float sgn = (d < 32) ? -1.f : 1.f;
  const int c = d >> 3, d7 = d & 7;

  for (int i = 0; i < 16; ++i) {
    const int nl = w * 16 + i;
    const int n = n0 + nl;
    const long base = ((long)(b * 1024 + n)) * 3072 + h * 64 + d;
    float q = bf2f(qkv[base]);
    float k = bf2f(qkv[base + 1024]);
    float v = bf2f(qkv[base + 2048]);
    v = l1 * v + l2 * vres[((long)(bh * 1024 + n)) * 64 + d];
    const float sinv = rope[n * 128 + d];
    const float cosv = rope[n * 128 + 64 + d];
    float s = q;
#pragma unroll
    for (int off = 1; off < 64; off <<= 1) s += __shfl_xor(s, off);
    const float qc = q - s * (1.f / 64.f);
    float vs = qc * qc;
#pragma unroll
    for (int off = 1; off < 64; off <<= 1) vs += __shfl_xor(vs, off);
    const float qn = qc * (1.f / sqrtf(vs * (1.f / 64.f) + 1e-5f)) * gq + bq;
    float s2 = k;
#pragma unroll
    for (int off = 1; off < 64; off <<= 1) s2 += __shfl_xor(s2, off);
    const float kc = k - s2 * (1.f / 64.f);
    float vs2 = kc * kc;
#pragma unroll
    for (int off = 1; off < 64; off <<= 1) vs2 += __shfl_xor(vs2, off);
    const float kn = kc * (1.f / sqrtf(vs2 * (1.f / 64.f) + 1e-5f)) * gk + bk;
    const float qo = __shfl_xor(qn, 32);
    const float ko = __shfl_xor(kn, 32);
    const float qr = qn * cosv + sgn * qo * sinv;
    const float kr = kn * cosv + sgn * ko * sinv;
    Q[(long)bh * 65536 + (long)n * 64 + d] = f2bf(qr);
    Ksw[(long)bh * 65536 + (long)n * 64 + ((c ^ (n & 7)) * 8 + d7)] = f2bf(kr);
    Vl[nl][d] = f2bf(v);
  }
  __syncthreads();
#pragma unroll
  for (int i = 0; i < 2; ++i) {
    const int task = i * 256 + t;
    const int dd = task >> 3, cc = task & 7;
    short8 o;
#pragma unroll
    for (int u = 0; u < 8; ++u) o[u] = (short)Vl[cc * 8 + u][dd];
    *(short8*)&VTsw[((long)(bh * 64 + dd)) * 1024 + n0 + ((cc ^ (dd & 7)) * 8)] = o;
  }
}

// ---------------- flash attention fwd v3: QBLK=128, double-buffered K/V -------
// Q [bh][n][64]; Ksw swizzled row-major; VTsw swizzled [bh][d][n].
// Grid (64, 8): each block owns 128 q-rows (2 sub-tiles of 64). K/V tiles are
// double-buffered: stage t+1 issued before computing t; ONE raw barrier +
// vmcnt(0) per kv-tile (stage latency hidden under ~2x compute).
__global__ __launch_bounds__(256, 2)
void attn_fwd3(const u16* __restrict__ Q, const u16* __restrict__ Ksw,
               const u16* __restrict__ VTsw, u16* __restrict__ Out) {
  __shared__ u16 Kl[2][64 * 64];
  __shared__ u16 Vl[2][64 * 64];
  __shared__ u16 Pl[4][2][16 * 64];
  const int t = threadIdx.x, w = t >> 6, l = t & 63;
  const int l15 = l & 15, lg = l >> 4;
  const int x7 = l15 & 7;
  const int bh = blockIdx.x, q0 = blockIdx.y * 128;
  const long bo = (long)bh * 65536;

  short8 qf[2][2];
#pragma unroll
  for (int sub = 0; sub < 2; ++sub)
#pragma unroll
    for (int ks = 0; ks < 2; ++ks)
      qf[sub][ks] = *(const short8*)&Q[bo + (long)(q0 + sub * 64 + w * 16 + l15) * 64 +
                                       ks * 32 + lg * 8];

  f32x4 acc[2][4] = {};
  float m_run[2] = {-1e30f, -1e30f};
  float l_run[2] = {0.f, 0.f};

  // one sub-tile's QK^T -> online softmax -> PV for kv-tile in buffer `cur`
  auto subt = [&](int kv, int cur, int sub) {
    f32x4 p[4];
#pragma unroll
    for (int mt = 0; mt < 4; ++mt) {
      f32x4 ps = {};
#pragma unroll
      for (int ks = 0; ks < 2; ++ks) {
        const short8 kf =
            *(const short8*)&Kl[cur][(mt * 16 + l15) * 64 + (((ks * 4 + lg) ^ x7) * 8)];
        ps = __builtin_amdgcn_mfma_f32_16x16x32_bf16(kf, qf[sub][ks], ps, 0, 0, 0);
      }
      p[mt] = ps;
    }
    float mx = p[0][0];
#pragma unroll
    for (int mt = 0; mt < 4; ++mt)
#pragma unroll
      for (int r = 0; r < 4; ++r) mx = fmaxf(mx, p[mt][r]);
    mx = fmaxf(mx, __shfl_xor(mx, 16));
    mx = fmaxf(mx, __shfl_xor(mx, 32));
    const float mnew = fmaxf(m_run[sub], mx * 0.125f);
    const float alpha = __expf(m_run[sub] - mnew);
    m_run[sub] = mnew;
    float sum = 0.f;
#pragma unroll
    for (int mt = 0; mt < 4; ++mt)
#pragma unroll
      for (int r = 0; r < 4; ++r) {
        const float e = __expf(p[mt][r] * 0.125f - mnew);
        p[mt][r] = e;
        sum += e;
      }
    sum += __shfl_xor(sum, 16);
    sum += __shfl_xor(sum, 32);
    l_run[sub] = l_run[sub] * alpha + sum;
    char* Plw = (char*)&Pl[w][sub][0];
#pragma unroll
    for (int mt = 0; mt < 4; ++mt) {
      const int c = mt * 2 + (lg >> 1);
      char* bp = Plw + l15 * 128 + ((c ^ x7) * 16) + (lg & 1) * 8;
      *(uint32_t*)bp = (uint32_t)f2bf(p[mt][0]) | ((uint32_t)f2bf(p[mt][1]) << 16);
      *(uint32_t*)(bp + 4) = (uint32_t)f2bf(p[mt][2]) | ((uint32_t)f2bf(p[mt][3]) << 16);
    }
#pragma unroll
    for (int mt = 0; mt < 4; ++mt)
#pragma unroll
      for (int r = 0; r < 4; ++r) acc[sub][mt][r] *= alpha;
#pragma unroll
    for (int ks = 0; ks < 2; ++ks) {
      const short8 pf = *(const short8*)(Plw + l15 * 128 + (((ks * 4 + lg) ^ x7) * 16));
#pragma unroll
      for (int mt = 0; mt < 4; ++mt) {
        const short8 vf =
            *(const short8*)&Vl[cur][(mt * 16 + l15) * 64 + (((ks * 4 + lg) ^ x7) * 8)];
        acc[sub][mt] = __builtin_amdgcn_mfma_f32_16x16x32_bf16(vf, pf, acc[sub][mt], 0, 0, 0);
      }
    }
  };

#define ASTAGE(KV, BUF)                                                          \
  {                                                                              \
    _Pragma("unroll") for (int i = 0; i < 2; ++i) {                              \
      const int idx = i * 256 + t;                                               \
      const int row = idx >> 3, seg = idx & 7;                                   \
      gload_lds16(Ksw + bo + (long)((KV) * 64 + row) * 64 + seg * 8,             \
                  (char*)&Kl[BUF][0] + idx * 16);                                \
      gload_lds16(VTsw + bo + (long)row * 1024 + (KV) * 64 + seg * 8,            \
                  (char*)&Vl[BUF][0] + idx * 16);                                \
    }                                                                            \
  }

#define AITER(KV, CUR, DO_STAGE)                                                 \
  {                                                                              \
    if (DO_STAGE) ASTAGE((KV) + 1, (CUR) ^ 1);                                   \
    subt((KV), (CUR), 0);                                                        \
    subt((KV), (CUR), 1);                                                        \
    asm volatile("s_waitcnt vmcnt(0)" ::: "memory");                             \
    __builtin_amdgcn_sched_barrier(0);                                           \
    __builtin_amdgcn_s_barrier();                                                \
    __builtin_amdgcn_sched_barrier(0);                                           \
  }

  // prologue: stage tile 0 into buf 0
  ASTAGE(0, 0)
  asm volatile("s_waitcnt vmcnt(0)" ::: "memory");
  __builtin_amdgcn_sched_barrier(0);
  __builtin_amdgcn_s_barrier();
  __builtin_amdgcn_sched_barrier(0);

  for (int kp = 0; kp < 8; ++kp) {
    AITER(2 * kp, 0, 1)
    AITER(2 * kp + 1, 1, (kp < 7))
  }
#undef AITER
#undef ASTAGE

  // epilogue: O[q][d] = O^T[d][q] / l; write [B,N,C]
  const int b = bh >> 4, h = bh & 15;
#pragma unroll
  for (int sub = 0; sub < 2; ++sub) {
    const int qrow = q0 + sub * 64 + w * 16 + l15;
    const float inv = 1.f / l_run[sub];
    const long obase = ((long)(b * 1024 + qrow)) * 1024 + h * 64;
#pragma unroll
    for (int mt = 0; mt < 4; ++mt) {
      const long o = obase + mt * 16 + lg * 4;
      *(uint32_t*)&Out[o] = (uint32_t)f2bf(acc[sub][mt][0] * inv) |
                            ((uint32_t)f2bf(acc[sub][mt][1] * inv) << 16);
      *(uint32_t*)&Out[o + 2] = (uint32_t)f2bf(acc[sub][mt][2] * inv) |
                                ((uint32_t)f2bf(acc[sub][mt][3] * inv) << 16);
    }
  }
}

extern "C" void kernel_launch(void* const* d_in, const int* in_sizes, int n_in,
                              void* d_out, int out_size, void* d_ws, size_t ws_size,
                              hipStream_t stream) {
  const float* x     = (const float*)d_in[0];
  const float* rope  = (const float*)d_in[1];
  const float* dte   = (const float*)d_in[2];
  const float* vres  = (const float*)d_in[3];
  const float* Wqkv  = (const float*)d_in[4];
  const float* bqkv  = (const float*)d_in[5];
  const float* Wdt   = (const float*)d_in[6];
  const float* bdt   = (const float*)d_in[7];
  const float* qn_g  = (const float*)d_in[8];
  const float* qn_b  = (const float*)d_in[9];
  const float* kn_g  = (const float*)d_in[10];
  const float* kn_b  = (const float*)d_in[11];
  const float* l1    = (const float*)d_in[12];
  const float* l2    = (const float*)d_in[13];
  const float* Wproj = (const float*)d_in[14];
  const float* bproj = (const float*)d_in[15];
  float* out = (float*)d_out;

  char* ws = (char*)d_ws;
  u16*   A_cat = (u16*)(ws);                    // [4096,2048] bf16
  u16*   W_cat = (u16*)(ws + 16777216);         // [3072,2048] bf16
  u16*   Wp    = (u16*)(ws + 29360128);         // [1024,1024] bf16
  u16*   qkvb  = (u16*)(ws + 31457280);         // [4096,3072] bf16
  u16*   Qb    = (u16*)(ws + 56623104);         // [64,1024,64] bf16
  u16*   Ksw   = (u16*)(ws + 65011712);         // swizzled K
  u16*   VTsw  = (u16*)(ws + 73400320);         // swizzled V^T
  u16*   AO    = (u16*)(ws + 81788928);         // [4096,1024] bf16
  // total ws usage: 90,177,536 bytes

  cvt_cat_bf16<<<2048, 256, 0, stream>>>(x, dte, A_cat, (long)4096 * 2048);
  cvt_cat_bf16<<<2048, 256, 0, stream>>>(Wqkv, Wdt, W_cat, (long)3072 * 2048);
  cvt_bf16<<<1024, 256, 0, stream>>>(Wproj, Wp, (long)1024 * 1024);
  // QKV+dt fused GEMM: 128^2 m97 structure, bf16 out
  gemm_bt_b16<<<dim3(32, 24), 256, 0, stream>>>(A_cat, W_cat, qkvb, bqkv, bdt,
                                                4096, 3072, 2048);
  fuse_qkv2<<<dim3(64, 16), 256, 0, stream>>>(qkvb, vres, rope, qn_g, qn_b, kn_g, kn_b,
                                              l1, l2, Qb, Ksw, VTsw);
  attn_fwd3<<<dim3(64, 8), 256, 0, stream>>>(Qb, Ksw, VTsw, AO);
  gemm_bt<<<dim3(32, 8), 256, 0, stream>>>(AO, Wp, out, bproj, nullptr, 4096, 1024, 1024);
}

// Round 7
// 170.435 us; speedup vs baseline: 1.0187x; 1.0022x over previous
//
#include <hip/hip_runtime.h>
#include <stdint.h>

typedef unsigned short u16;
typedef __attribute__((ext_vector_type(8))) short short8;
typedef __attribute__((ext_vector_type(4))) float f32x4;
typedef __attribute__((ext_vector_type(4))) unsigned short u16x4;

#define DEVI __device__ __forceinline__

DEVI u16 f2bf(float f) {
  uint32_t u = __builtin_bit_cast(uint32_t, f);
  u += 0x7fffu + ((u >> 16) & 1u);
  return (u16)(u >> 16);
}

DEVI float bf2f(u16 u) {
  uint32_t v = ((uint32_t)u) << 16;
  return __builtin_bit_cast(float, v);
}

DEVI void gload_lds16(const void* g, void* l) {
  __builtin_amdgcn_global_load_lds(
      (const __attribute__((address_space(1))) void*)g,
      (__attribute__((address_space(3))) void*)(uint32_t)(uintptr_t)l,
      16, 0, 0);
}

// ---------------- convert / concat fp32 -> bf16 ----------------
__global__ void cvt_cat_bf16(const float* __restrict__ a, const float* __restrict__ b,
                             u16* __restrict__ dst, long total) {
  for (long i = ((long)blockIdx.x * 256 + threadIdx.x) * 4; i < total;
       i += (long)gridDim.x * 1024) {
    const long row = i >> 11;
    const long c = i & 2047;
    const float* src = (c < 1024) ? (a + row * 1024 + c) : (b + row * 1024 + (c - 1024));
    const float4 v = *(const float4*)src;
    u16x4 o = {f2bf(v.x), f2bf(v.y), f2bf(v.z), f2bf(v.w)};
    *(u16x4*)(dst + i) = o;
  }
}

__global__ void cvt_bf16(const float* __restrict__ a, u16* __restrict__ dst, long total) {
  for (long i = ((long)blockIdx.x * 256 + threadIdx.x) * 4; i < total;
       i += (long)gridDim.x * 1024) {
    const float4 v = *(const float4*)(a + i);
    u16x4 o = {f2bf(v.x), f2bf(v.y), f2bf(v.z), f2bf(v.w)};
    *(u16x4*)(dst + i) = o;
  }
}

// ---------------- bf16 GEMM 128^2 (m97 structure), fp32 out — proj ------------
__global__ __launch_bounds__(256, 2)
void gemm_bt(const u16* __restrict__ A, const u16* __restrict__ B,
             float* __restrict__ C, const float* __restrict__ bias1,
             const float* __restrict__ bias2, int M, int N, int K) {
  __shared__ u16 As[128 * 32];
  __shared__ u16 Bs[128 * 32];
  const int t = threadIdx.x;
  const int w = t >> 6, l = t & 63;
  const int l15 = l & 15, lg = l >> 4;
  const int bm = blockIdx.x, bn = blockIdx.y;
  const int wr = (w >> 1) * 64, wc = (w & 1) * 64;
  f32x4 acc[4][4] = {};
  const int c0 = w * 64 + l;

  for (int kt = 0; kt < (K >> 5); ++kt) {
#pragma unroll
    for (int i = 0; i < 2; ++i) {
      const int c = i * 256 + c0;
      const int row = c >> 2, seg = c & 3;
      gload_lds16(A + (long)(bm * 128 + row) * K + kt * 32 + seg * 8,
                  (char*)As + w * 1024 + i * 4096);
      gload_lds16(B + (long)(bn * 128 + row) * K + kt * 32 + seg * 8,
                  (char*)Bs + w * 1024 + i * 4096);
    }
    __syncthreads();
    short8 af[4], bfr[4];
#pragma unroll
    for (int m = 0; m < 4; ++m)
      af[m] = *(const short8*)&As[(wr + m * 16 + l15) * 32 + lg * 8];
#pragma unroll
    for (int n = 0; n < 4; ++n)
      bfr[n] = *(const short8*)&Bs[(wc + n * 16 + l15) * 32 + lg * 8];
#pragma unroll
    for (int m = 0; m < 4; ++m)
#pragma unroll
      for (int n = 0; n < 4; ++n)
        acc[m][n] = __builtin_amdgcn_mfma_f32_16x16x32_bf16(af[m], bfr[n], acc[m][n], 0, 0, 0);
    __syncthreads();
  }
#pragma unroll
  for (int m = 0; m < 4; ++m) {
    const int row0 = bm * 128 + wr + m * 16 + lg * 4;
#pragma unroll
    for (int n = 0; n < 4; ++n) {
      const int col = bn * 128 + wc + n * 16 + l15;
      float bia = 0.f;
      if (bias1) bia += bias1[col];
      if (bias2) bia += bias2[col];
#pragma unroll
      for (int r = 0; r < 4; ++r)
        C[(long)(row0 + r) * N + col] = acc[m][n][r] + bia;
    }
  }
}

// ---------------- same structure, bf16 out — QKV+dt fused GEMM ----------------
__global__ __launch_bounds__(256, 2)
void gemm_bt_b16(const u16* __restrict__ A, const u16* __restrict__ B,
                 u16* __restrict__ C, const float* __restrict__ bias1,
                 const float* __restrict__ bias2, int M, int N, int K) {
  __shared__ u16 As[128 * 32];
  __shared__ u16 Bs[128 * 32];
  const int t = threadIdx.x;
  const int w = t >> 6, l = t & 63;
  const int l15 = l & 15, lg = l >> 4;
  const int bm = blockIdx.x, bn = blockIdx.y;
  const int wr = (w >> 1) * 64, wc = (w & 1) * 64;
  f32x4 acc[4][4] = {};
  const int c0 = w * 64 + l;

  for (int kt = 0; kt < (K >> 5); ++kt) {
#pragma unroll
    for (int i = 0; i < 2; ++i) {
      const int c = i * 256 + c0;
      const int row = c >> 2, seg = c & 3;
      gload_lds16(A + (long)(bm * 128 + row) * K + kt * 32 + seg * 8,
                  (char*)As + w * 1024 + i * 4096);
      gload_lds16(B + (long)(bn * 128 + row) * K + kt * 32 + seg * 8,
                  (char*)Bs + w * 1024 + i * 4096);
    }
    __syncthreads();
    short8 af[4], bfr[4];
#pragma unroll
    for (int m = 0; m < 4; ++m)
      af[m] = *(const short8*)&As[(wr + m * 16 + l15) * 32 + lg * 8];
#pragma unroll
    for (int n = 0; n < 4; ++n)
      bfr[n] = *(const short8*)&Bs[(wc + n * 16 + l15) * 32 + lg * 8];
#pragma unroll
    for (int m = 0; m < 4; ++m)
#pragma unroll
      for (int n = 0; n < 4; ++n)
        acc[m][n] = __builtin_amdgcn_mfma_f32_16x16x32_bf16(af[m], bfr[n], acc[m][n], 0, 0, 0);
    __syncthreads();
  }
#pragma unroll
  for (int m = 0; m < 4; ++m) {
    const int row0 = bm * 128 + wr + m * 16 + lg * 4;
#pragma unroll
    for (int n = 0; n < 4; ++n) {
      const int col = bn * 128 + wc + n * 16 + l15;
      float bia = 0.f;
      if (bias1) bia += bias1[col];
      if (bias2) bia += bias2[col];
#pragma unroll
      for (int r = 0; r < 4; ++r)
        C[(long)(row0 + r) * N + col] = f2bf(acc[m][n][r] + bia);
    }
  }
}

// ---------------- fuse: split qkv (bf16), vres mix, LN(q,k), RoPE ----------------
__global__ __launch_bounds__(256)
void fuse_qkv2(const u16* __restrict__ qkv, const float* __restrict__ vres,
               const float* __restrict__ rope,
               const float* __restrict__ qg, const float* __restrict__ qb,
               const float* __restrict__ kg, const float* __restrict__ kb,
               const float* __restrict__ pl1, const float* __restrict__ pl2,
               u16* __restrict__ Q, u16* __restrict__ Ksw, u16* __restrict__ VTsw) {
  __shared__ u16 Vl[64][72];
  const int t = threadIdx.x, w = t >> 6, d = t & 63;
  const int bh = blockIdx.x, ntile = blockIdx.y;
  const int b = bh >> 4, h = bh & 15, n0 = ntile * 64;
  const float l1 = pl1[0], l2 = pl2[0];
  const float gq = qg[d], bq = qb[d];
  const float gk = kg[d], bk = kb[d];
  const float sgn = (d < 32) ? -1.f : 1.f;
  const int c = d >> 3, d7 = d & 7;

  for (int i = 0; i < 16; ++i) {
    const int nl = w * 16 + i;
    const int n = n0 + nl;
    const long base = ((long)(b * 1024 + n)) * 3072 + h * 64 + d;
    float q = bf2f(qkv[base]);
    float k = bf2f(qkv[base + 1024]);
    float v = bf2f(qkv[base + 2048]);
    v = l1 * v + l2 * vres[((long)(bh * 1024 + n)) * 64 + d];
    const float sinv = rope[n * 128 + d];
    const float cosv = rope[n * 128 + 64 + d];
    float s = q;
#pragma unroll
    for (int off = 1; off < 64; off <<= 1) s += __shfl_xor(s, off);
    const float qc = q - s * (1.f / 64.f);
    float vs = qc * qc;
#pragma unroll
    for (int off = 1; off < 64; off <<= 1) vs += __shfl_xor(vs, off);
    const float qn = qc * (1.f / sqrtf(vs * (1.f / 64.f) + 1e-5f)) * gq + bq;
    float s2 = k;
#pragma unroll
    for (int off = 1; off < 64; off <<= 1) s2 += __shfl_xor(s2, off);
    const float kc = k - s2 * (1.f / 64.f);
    float vs2 = kc * kc;
#pragma unroll
    for (int off = 1; off < 64; off <<= 1) vs2 += __shfl_xor(vs2, off);
    const float kn = kc * (1.f / sqrtf(vs2 * (1.f / 64.f) + 1e-5f)) * gk + bk;
    const float qo = __shfl_xor(qn, 32);
    const float ko = __shfl_xor(kn, 32);
    const float qr = qn * cosv + sgn * qo * sinv;
    const float kr = kn * cosv + sgn * ko * sinv;
    Q[(long)bh * 65536 + (long)n * 64 + d] = f2bf(qr);
    Ksw[(long)bh * 65536 + (long)n * 64 + ((c ^ (n & 7)) * 8 + d7)] = f2bf(kr);
    Vl[nl][d] = f2bf(v);
  }
  __syncthreads();
#pragma unroll
  for (int i = 0; i < 2; ++i) {
    const int task = i * 256 + t;
    const int dd = task >> 3, cc = task & 7;
    short8 o;
#pragma unroll
    for (int u = 0; u < 8; ++u) o[u] = (short)Vl[cc * 8 + u][dd];
    *(short8*)&VTsw[((long)(bh * 64 + dd)) * 1024 + n0 + ((cc ^ (dd & 7)) * 8)] = o;
  }
}

// ---------------- flash attention fwd v4: QBLK=64 + double-buffered K/V -------
// v2 structure (4 blocks/CU) + stage-early: tile t+1's global_load_lds issued
// into the free buffer BEFORE computing tile t; one vmcnt(0)+s_barrier per
// tile (stage latency hidden under QK^T/softmax/PV compute).
// LDS = 16K(K) + 16K(V) + 8K(P) = 40 KB -> exactly 4 blocks/CU.
__global__ __launch_bounds__(256, 4)
void attn_fwd4(const u16* __restrict__ Q, const u16* __restrict__ Ksw,
               const u16* __restrict__ VTsw, u16* __restrict__ Out) {
  __shared__ u16 Kl[2][64 * 64];
  __shared__ u16 Vl[2][64 * 64];
  __shared__ u16 Pl[4][16 * 64];
  const int t = threadIdx.x, w = t >> 6, l = t & 63;
  const int l15 = l & 15, lg = l >> 4;
  const int x7 = l15 & 7;
  const int bh = blockIdx.x, q0 = blockIdx.y * 64;
  const long bo = (long)bh * 65536;
  char* Plw = (char*)&Pl[w][0];

  const int qrow = q0 + w * 16 + l15;
  short8 qf[2];
#pragma unroll
  for (int ks = 0; ks < 2; ++ks)
    qf[ks] = *(const short8*)&Q[bo + (long)qrow * 64 + ks * 32 + lg * 8];

  f32x4 acc[4] = {};
  float m_run = -1e30f, l_run = 0.f;

#define ASTAGE(KV, BUF)                                                          \
  {                                                                              \
    _Pragma("unroll") for (int i = 0; i < 2; ++i) {                              \
      const int idx = i * 256 + t;                                               \
      const int row = idx >> 3, seg = idx & 7;                                   \
      gload_lds16(Ksw + bo + (long)((KV) * 64 + row) * 64 + seg * 8,             \
                  (char*)&Kl[BUF][0] + idx * 16);                                \
      gload_lds16(VTsw + bo + (long)row * 1024 + (KV) * 64 + seg * 8,            \
                  (char*)&Vl[BUF][0] + idx * 16);                                \
    }                                                                            \
  }

#define AITER(KV, CUR, DO_STAGE)                                                 \
  {                                                                              \
    if (DO_STAGE) ASTAGE((KV) + 1, (CUR) ^ 1);                                   \
    f32x4 p[4];                                                                  \
    _Pragma("unroll") for (int mt = 0; mt < 4; ++mt) {                           \
      f32x4 ps = {};                                                             \
      _Pragma("unroll") for (int ks = 0; ks < 2; ++ks) {                         \
        const short8 kf = *(const short8*)&Kl[CUR][(mt * 16 + l15) * 64 +        \
                                                   (((ks * 4 + lg) ^ x7) * 8)];  \
        ps = __builtin_amdgcn_mfma_f32_16x16x32_bf16(kf, qf[ks], ps, 0, 0, 0);   \
      }                                                                          \
      p[mt] = ps;                                                                \
    }                                                                            \
    float mx = p[0][0];                                                          \
    _Pragma("unroll") for (int mt = 0; mt < 4; ++mt)                             \
      _Pragma("unroll") for (int r = 0; r < 4; ++r) mx = fmaxf(mx, p[mt][r]);    \
    mx = fmaxf(mx, __shfl_xor(mx, 16));                                          \
    mx = fmaxf(mx, __shfl_xor(mx, 32));                                          \
    const float mnew = fmaxf(m_run, mx * 0.125f);                                \
    const float alpha = __expf(m_run - mnew);                                    \
    m_run = mnew;                                                                \
    float sum = 0.f;                                                             \
    _Pragma("unroll") for (int mt = 0; mt < 4; ++mt)                             \
      _Pragma("unroll") for (int r = 0; r < 4; ++r) {                            \
        const float e = __expf(p[mt][r] * 0.125f - mnew);                        \
        p[mt][r] = e;                                                            \
        sum += e;                                                                \
      }                                                                          \
    sum += __shfl_xor(sum, 16);                                                  \
    sum += __shfl_xor(sum, 32);                                                  \
    l_run = l_run * alpha + sum;                                                 \
    _Pragma("unroll") for (int mt = 0; mt < 4; ++mt) {                           \
      const int c = mt * 2 + (lg >> 1);                                          \
      char* bp = Plw + l15 * 128 + ((c ^ x7) * 16) + (lg & 1) * 8;               \
      *(uint32_t*)bp = (uint32_t)f2bf(p[mt][0]) | ((uint32_t)f2bf(p[mt][1]) << 16); \
      *(uint32_t*)(bp + 4) =                                                     \
          (uint32_t)f2bf(p[mt][2]) | ((uint32_t)f2bf(p[mt][3]) << 16);           \
    }                                                                            \
    _Pragma("unroll") for (int mt = 0; mt < 4; ++mt)                             \
      _Pragma("unroll") for (int r = 0; r < 4; ++r) acc[mt][r] *= alpha;         \
    _Pragma("unroll") for (int ks = 0; ks < 2; ++ks) {                           \
      const short8 pf =                                                          \
          *(const short8*)(Plw + l15 * 128 + (((ks * 4 + lg) ^ x7) * 16));       \
      _Pragma("unroll") for (int mt = 0; mt < 4; ++mt) {                         \
        const short8 vf = *(const short8*)&Vl[CUR][(mt * 16 + l15) * 64 +        \
                                                   (((ks * 4 + lg) ^ x7) * 8)];  \
        acc[mt] = __builtin_amdgcn_mfma_f32_16x16x32_bf16(vf, pf, acc[mt], 0, 0, 0); \
      }                                                                          \
    }                                                                            \
    asm volatile("s_waitcnt vmcnt(0)" ::: "memory");                             \
    __builtin_amdgcn_sched_barrier(0);                                           \
    __builtin_amdgcn_s_barrier();                                                \
    __builtin_amdgcn_sched_barrier(0);                                           \
  }

  // prologue: stage tile 0 into buf 0
  ASTAGE(0, 0)
  asm volatile("s_waitcnt vmcnt(0)" ::: "memory");
  __builtin_amdgcn_sched_barrier(0);
  __builtin_amdgcn_s_barrier();
  __builtin_amdgcn_sched_barrier(0);

  for (int kp = 0; kp < 8; ++kp) {
    AITER(2 * kp, 0, 1)
    AITER(2 * kp + 1, 1, (kp < 7))
  }
#undef AITER
#undef ASTAGE

  // epilogue: O[q][d] = O^T[d][q] / l; write [B,N,C]
  const int b = bh >> 4, h = bh & 15;
  const float inv = 1.f / l_run;
  const long obase = ((long)(b * 1024 + qrow)) * 1024 + h * 64;
#pragma unroll
  for (int mt = 0; mt < 4; ++mt) {
    const long o = obase + mt * 16 + lg * 4;
    *(uint32_t*)&Out[o] =
        (uint32_t)f2bf(acc[mt][0] * inv) | ((uint32_t)f2bf(acc[mt][1] * inv) << 16);
    *(uint32_t*)&Out[o + 2] =
        (uint32_t)f2bf(acc[mt][2] * inv) | ((uint32_t)f2bf(acc[mt][3] * inv) << 16);
  }
}

extern "C" void kernel_launch(void* const* d_in, const int* in_sizes, int n_in,
                              void* d_out, int out_size, void* d_ws, size_t ws_size,
                              hipStream_t stream) {
  const float* x     = (const float*)d_in[0];
  const float* rope  = (const float*)d_in[1];
  const float* dte   = (const float*)d_in[2];
  const float* vres  = (const float*)d_in[3];
  const float* Wqkv  = (const float*)d_in[4];
  const float* bqkv  = (const float*)d_in[5];
  const float* Wdt   = (const float*)d_in[6];
  const float* bdt   = (const float*)d_in[7];
  const float* qn_g  = (const float*)d_in[8];
  const float* qn_b  = (const float*)d_in[9];
  const float* kn_g  = (const float*)d_in[10];
  const float* kn_b  = (const float*)d_in[11];
  const float* l1    = (const float*)d_in[12];
  const float* l2    = (const float*)d_in[13];
  const float* Wproj = (const float*)d_in[14];
  const float* bproj = (const float*)d_in[15];
  float* out = (float*)d_out;

  char* ws = (char*)d_ws;
  u16*   A_cat = (u16*)(ws);                    // [4096,2048] bf16
  u16*   W_cat = (u16*)(ws + 16777216);         // [3072,2048] bf16
  u16*   Wp    = (u16*)(ws + 29360128);         // [1024,1024] bf16
  u16*   qkvb  = (u16*)(ws + 31457280);         // [4096,3072] bf16
  u16*   Qb    = (u16*)(ws + 56623104);         // [64,1024,64] bf16
  u16*   Ksw   = (u16*)(ws + 65011712);         // swizzled K
  u16*   VTsw  = (u16*)(ws + 73400320);         // swizzled V^T
  u16*   AO    = (u16*)(ws + 81788928);         // [4096,1024] bf16
  // total ws usage: 90,177,536 bytes

  cvt_cat_bf16<<<2048, 256, 0, stream>>>(x, dte, A_cat, (long)4096 * 2048);
  cvt_cat_bf16<<<2048, 256, 0, stream>>>(Wqkv, Wdt, W_cat, (long)3072 * 2048);
  cvt_bf16<<<1024, 256, 0, stream>>>(Wproj, Wp, (long)1024 * 1024);
  // QKV+dt fused GEMM: 128^2 m97 structure, bf16 out
  gemm_bt_b16<<<dim3(32, 24), 256, 0, stream>>>(A_cat, W_cat, qkvb, bqkv, bdt,
                                                4096, 3072, 2048);
  fuse_qkv2<<<dim3(64, 16), 256, 0, stream>>>(qkvb, vres, rope, qn_g, qn_b, kn_g, kn_b,
                                              l1, l2, Qb, Ksw, VTsw);
  attn_fwd4<<<dim3(64, 16), 256, 0, stream>>>(Qb, Ksw, VTsw, AO);
  gemm_bt<<<dim3(32, 8), 256, 0, stream>>>(AO, Wp, out, bproj, nullptr, 4096, 1024, 1024);
}